// Round 9
// baseline (467.494 us; speedup 1.0000x reference)
//
#include <hip/hip_runtime.h>
#include <math.h>

// ---- problem constants ----
#define NB      8
#define C_IN    3
#define HIMG    512
#define WIMG    512
#define C1      64      // conv1 out channels
#define HMID    256     // after pool1
#define WMID    256
#define C2      128     // conv2 out channels (C_FEAT)
#define HFT     128     // after pool2
#define WFT     128
#define NROIS   256
#define ROI_FT  32
#define SPP_DIM 2688    // 128*(1+4+16)
#define FC1_OUT 256
#define NCLS    1000

typedef unsigned short ushort;
typedef __attribute__((ext_vector_type(8))) short short8;
typedef __attribute__((ext_vector_type(4))) float f32x4;

#define GLOBAL_AS __attribute__((address_space(1)))
#define LDS_AS    __attribute__((address_space(3)))

static __device__ __forceinline__ ushort f2bf(float f) {
    unsigned u = __builtin_bit_cast(unsigned, f);
    unsigned r = (u + 0x7fffu + ((u >> 16) & 1u)) >> 16;   // RNE
    return (ushort)r;
}
static __device__ __forceinline__ float bf2f(ushort u) {
    return __builtin_bit_cast(float, (unsigned)u << 16);
}

// ---------------------------------------------------------------------------
// Kernel W2: transpose w2 -> Wt [tap][oc][ci] bf16; also zero the zero-page.
// ---------------------------------------------------------------------------
__global__ __launch_bounds__(256)
void k_w2t(const float* __restrict__ w2, ushort* __restrict__ Wt,
           ushort* __restrict__ zp)
{
    int i = blockIdx.x * 256 + threadIdx.x;      // 9*128*64 = 73728
    if (blockIdx.x == 0 && threadIdx.x < 64) zp[threadIdx.x] = 0;
    if (i >= 9 * 128 * 64) return;
    int tap = i >> 13;
    int rem = i & 8191;
    int oc  = rem >> 6;
    int ci  = rem & 63;
    Wt[i] = f2bf(w2[(oc * 64 + ci) * 9 + tap]);
}

// ---------------------------------------------------------------------------
// Kernel W1: w1 [oc][ci][3][3] fp32 -> W1t [oc][k] bf16, k = tap*3+ci, pad 32
// ---------------------------------------------------------------------------
__global__ __launch_bounds__(256)
void k_w1t(const float* __restrict__ w1, ushort* __restrict__ W1t)
{
    int i = blockIdx.x * 256 + threadIdx.x;      // 64*32 = 2048
    if (i >= 2048) return;
    int oc = i >> 5, k = i & 31;
    float v = 0.f;
    if (k < 27) {
        int tap = k / 3, ci = k - 3 * tap;
        v = w1[oc * 27 + ci * 9 + tap];
    }
    W1t[i] = f2bf(v);
}

// ---------------------------------------------------------------------------
// Kernel F1T: fc1_w [2688][256] f32 -> f1T [256][2688] bf16 (LDS tile transp)
// ---------------------------------------------------------------------------
__global__ __launch_bounds__(256)
void k_f1t(const float* __restrict__ w, ushort* __restrict__ o)
{
    __shared__ float sm[64][65];
    const int k0 = blockIdx.x * 64;     // 42 blocks
    const int n0 = blockIdx.y * 64;     // 4 blocks
    #pragma unroll
    for (int s = 0; s < 16; ++s) {
        int idx = s * 256 + threadIdx.x;
        int lk = idx >> 6, ln = idx & 63;
        sm[lk][ln] = w[(size_t)(k0 + lk) * FC1_OUT + n0 + ln];
    }
    __syncthreads();
    #pragma unroll
    for (int s = 0; s < 16; ++s) {
        int idx = s * 256 + threadIdx.x;
        int ln = idx >> 6, lk = idx & 63;
        o[(size_t)(n0 + ln) * SPP_DIM + k0 + lk] = f2bf(sm[lk][ln]);
    }
}

// ---------------------------------------------------------------------------
// Kernel F2T: fc2_w [256][1000] f32 -> f2T [1024][256] bf16 (zero-padded rows)
// ---------------------------------------------------------------------------
__global__ __launch_bounds__(256)
void k_f2t(const float* __restrict__ w, ushort* __restrict__ o)
{
    __shared__ float sm[64][65];
    const int k0 = blockIdx.x * 64;     // 4 blocks
    const int n0 = blockIdx.y * 64;     // 16 blocks (cols padded to 1024)
    #pragma unroll
    for (int s = 0; s < 16; ++s) {
        int idx = s * 256 + threadIdx.x;
        int lk = idx >> 6, ln = idx & 63;
        sm[lk][ln] = (n0 + ln < NCLS) ? w[(size_t)(k0 + lk) * NCLS + n0 + ln] : 0.f;
    }
    __syncthreads();
    #pragma unroll
    for (int s = 0; s < 16; ++s) {
        int idx = s * 256 + threadIdx.x;
        int ln = idx >> 6, lk = idx & 63;
        o[(size_t)(n0 + ln) * FC1_OUT + k0 + lk] = f2bf(sm[lk][ln]);
    }
}

// ---------------------------------------------------------------------------
// Kernel A: conv1 via bf16 MFMA implicit GEMM + bias + relu + 2x2 pool.
// ---------------------------------------------------------------------------
__global__ __launch_bounds__(512, 4)
void k_conv1_mfma(const float* __restrict__ x, const ushort* __restrict__ W1t,
                  const float* __restrict__ b1, ushort* __restrict__ mid)
{
    __shared__ ushort sm_x[3 * 10 * 36 + 8];     // input tile, row stride 36
    __shared__ ushort sm_o[4 * 16 * 64];         // pooled out [py][px][oc] 8KB

    const int tid = threadIdx.x;
    const int tx = blockIdx.x;    // 0..15 (32 conv cols)
    const int ty = blockIdx.y;    // 0..63 (8 conv rows)
    const int b  = blockIdx.z;

    const int cy0 = ty * 8, cx0 = tx * 32;

    for (int t = tid; t < 3 * 10 * 34; t += 512) {
        int ci  = t / 340;
        int rem = t - ci * 340;
        int r = rem / 34, c = rem - r * 34;
        int gy = cy0 - 1 + r, gx = cx0 - 1 + c;
        float v = 0.f;
        if ((unsigned)gy < (unsigned)HIMG && (unsigned)gx < (unsigned)WIMG)
            v = x[((b * C_IN + ci) * HIMG + gy) * WIMG + gx];
        sm_x[ci * 360 + r * 36 + c] = f2bf(v);
    }
    __syncthreads();

    const int l   = tid & 63;
    const int wid = tid >> 6;
    const int wm  = wid & 3;       // conv-x offset wm*8
    const int wn  = wid >> 2;      // oc offset wn*32
    const int c16 = l & 15;
    const int hi  = l >> 4;
    const int ylane = (c16 >> 1) & 1;
    const int xlane = ((c16 >> 2) << 1) | (c16 & 1);
    const int xloc  = wm * 8 + xlane;

    int offj[8];
    #pragma unroll
    for (int j = 0; j < 8; ++j) {
        int k = hi * 8 + j;
        int tap = k / 3, ci = k - 3 * tap;
        int dy = tap / 3, dx = tap - 3 * dy;
        offj[j] = (k < 27) ? (ci * 360 + dy * 36 + dx) : 0;
    }

    short8 bf[2];
    #pragma unroll
    for (int fn = 0; fn < 2; ++fn)
        bf[fn] = *(const short8*)(W1t + (wn * 32 + fn * 16 + c16) * 32 + hi * 8);

    f32x4 acc[4][2] = {};
    #pragma unroll
    for (int fm = 0; fm < 4; ++fm) {
        int base = (2 * fm + ylane) * 36 + xloc;
        union { ushort u[8]; short8 s; } av;
        #pragma unroll
        for (int j = 0; j < 8; ++j) av.u[j] = sm_x[offj[j] + base];
        #pragma unroll
        for (int fn = 0; fn < 2; ++fn)
            acc[fm][fn] = __builtin_amdgcn_mfma_f32_16x16x32_bf16(
                av.s, bf[fn], acc[fm][fn], 0, 0, 0);
    }

    const int pxl = wm * 4 + hi;   // pooled px local 0..15
    #pragma unroll
    for (int fn = 0; fn < 2; ++fn) {
        int oc = wn * 32 + fn * 16 + c16;
        float bb = b1[oc];
        #pragma unroll
        for (int fm = 0; fm < 4; ++fm) {
            f32x4 a4 = acc[fm][fn];
            float m = fmaxf(fmaxf(a4[0], a4[1]), fmaxf(a4[2], a4[3]));
            sm_o[(fm * 16 + pxl) * 64 + oc] = f2bf(fmaxf(m + bb, 0.f));
        }
    }
    __syncthreads();
    {
        int row = tid >> 7;        // 0..3 local pooled row
        int off = tid & 127;       // 128 x 16B = 2KB per row
        uint4 v = *(const uint4*)(sm_o + row * (16 * 64) + off * 8);
        int py = ty * 4 + row;
        uint4* dst = (uint4*)(mid + ((size_t)(b * HMID + py) * WMID + tx * 16) * C1) + off;
        *dst = v;
    }
}

// ---------------------------------------------------------------------------
// Kernel B: conv2 bf16 MFMA — PERSISTENT double-buffered pipeline.
// Grid 256 blocks (1/CU) x 512 thr; each block owns 8 consecutive tiles
// (tile = 8y x 32x conv pos, 128 oc). Per tile: ISSUE next tile's
// global_load_lds batch FIRST, then K-loop on current buffer — stage latency
// hides under ~4K cycles of MFMA (T14 issue-early / 2-phase pipeline).
// R8's dual register prefetch (A from LDS, B from L2) retained.
// ---------------------------------------------------------------------------
__global__ __launch_bounds__(512, 2)
void k_conv2_mfma(const ushort* __restrict__ mid, const ushort* __restrict__ Wt,
                  const float* __restrict__ b2, const ushort* __restrict__ zp,
                  ushort* __restrict__ feat)
{
    __shared__ uint4  sm_buf[2][2720];   // 2 x 42.5KB halo (340 pos x 8 gran)
    __shared__ ushort sm_o[4 * 16 * 128];

    const int tid = threadIdx.x;
    const int l   = tid & 63;
    const int wid = tid >> 6;
    const int wm  = wid & 3;        // x-offset wm*8
    const int wn  = wid >> 2;       // oc-offset wn*64
    const int c16 = l & 15;
    const int hi  = l >> 4;
    const int ylane = (c16 >> 1) & 1;
    const int xlane = ((c16 >> 2) << 1) | (c16 & 1);
    const int pos00 = ylane * 34 + wm * 8 + xlane;
    const ushort* wbp = Wt + ((size_t)(wn * 64 + c16) * 64 + 8 * hi);

    const int t0 = blockIdx.x * 8;       // 256 blocks x 8 tiles = 2048

    auto stage = [&](int bufi, int tile) {
        int tb = tile >> 8, rem = tile & 255;
        int tty = rem >> 3, ttx = rem & 7;
        int cy0 = tty * 8 - 1, cx0 = ttx * 32 - 1;
        #pragma unroll
        for (int s = 0; s < 6; ++s) {
            int t = s * 512 + tid;
            if (t < 2720) {
                int pos = t >> 3, g = t & 7;
                int hy = pos / 34, hx = pos - hy * 34;
                int gy = cy0 + hy, gx = cx0 + hx;
                bool ok = ((unsigned)gy < (unsigned)HMID) && ((unsigned)gx < (unsigned)WMID);
                const ushort* src = ok
                    ? mid + (((size_t)(tb * HMID + gy) * WMID + gx) * C1 + (g ^ (pos & 7)) * 8)
                    : zp;
                __builtin_amdgcn_global_load_lds((const GLOBAL_AS void*)src,
                                                 (LDS_AS void*)&sm_buf[bufi][t], 16, 0, 0);
            }
        }
    };

    stage(0, t0);
    __syncthreads();                       // prologue: tile 0 staged

    for (int i = 0; i < 8; ++i) {
        const int cur = i & 1;
        if (i < 7) stage(cur ^ 1, t0 + i + 1);   // issue-early: hides under K-loop

        const int tile = t0 + i;
        const int b  = tile >> 8;
        const int rem = tile & 255;
        const int ty = rem >> 3, tx = rem & 7;
        const uint4* smc = &sm_buf[cur][0];

        f32x4 acc[4][4] = {};
        short8 acur[4], anxt[4], bcur[4], bnxt[4];

        #pragma unroll
        for (int fm = 0; fm < 4; ++fm) {
            int pos = pos00 + fm * 68;
            acur[fm] = __builtin_bit_cast(short8, smc[pos * 8 + (hi ^ (pos & 7))]);
        }
        #pragma unroll
        for (int fn = 0; fn < 4; ++fn)
            bcur[fn] = *(const short8*)(wbp + fn * 1024);

        #pragma unroll
        for (int c = 0; c < 18; ++c) {          // chunk: tap = c>>1, k0 = c&1
            const int cn   = (c < 17) ? c + 1 : 17;
            const int tapn = cn >> 1, k0n = cn & 1;
            const int dyn  = tapn / 3, dxn = tapn - 3 * dyn;
            #pragma unroll
            for (int fm = 0; fm < 4; ++fm) {    // prefetch next A (LDS)
                int pos = pos00 + dyn * 34 + dxn + fm * 68;
                int gi  = (hi + k0n * 4) ^ (pos & 7);
                anxt[fm] = __builtin_bit_cast(short8, smc[pos * 8 + gi]);
            }
            const ushort* wnp = wbp + tapn * 8192 + k0n * 32;
            #pragma unroll
            for (int fn = 0; fn < 4; ++fn)      // prefetch next B (L2)
                bnxt[fn] = *(const short8*)(wnp + fn * 1024);

            __builtin_amdgcn_s_setprio(1);
            #pragma unroll
            for (int fm = 0; fm < 4; ++fm)
                #pragma unroll
                for (int fn = 0; fn < 4; ++fn)
                    acc[fm][fn] = __builtin_amdgcn_mfma_f32_16x16x32_bf16(
                        acur[fm], bcur[fn], acc[fm][fn], 0, 0, 0);
            __builtin_amdgcn_s_setprio(0);

            #pragma unroll
            for (int q = 0; q < 4; ++q) { acur[q] = anxt[q]; bcur[q] = bnxt[q]; }
        }

        // epilogue: pool 2x2 -> sm_o -> linear stores
        const int pxl = wm * 4 + hi;
        #pragma unroll
        for (int fn = 0; fn < 4; ++fn) {
            int oc = wn * 64 + fn * 16 + c16;
            float bb = b2[oc];
            #pragma unroll
            for (int fm = 0; fm < 4; ++fm) {
                f32x4 a4 = acc[fm][fn];
                float m = fmaxf(fmaxf(a4[0], a4[1]), fmaxf(a4[2], a4[3]));
                sm_o[(fm * 16 + pxl) * 128 + oc] = f2bf(fmaxf(m + bb, 0.f));
            }
        }
        __syncthreads();                   // sm_o ready (stage loads long done)
        const int py0 = ty * 4;
        #pragma unroll
        for (int pass = 0; pass < 2; ++pass) {
            int idx = pass * 512 + tid;    // 0..1023
            int row = idx >> 8;            // 0..3
            int off = idx & 255;           // 256 x 16B = 4KB per row
            uint4 v = *(const uint4*)(sm_o + row * (16 * 128) + off * 8);
            uint4* dst = (uint4*)(feat + ((size_t)(b * HFT + py0 + row) * WFT + tx * 16) * C2) + off;
            *dst = v;
        }
        __syncthreads();                   // sm_o reads + next buf staged by all
    }
}

// ---------------------------------------------------------------------------
// Kernel C: ROI crop + SPP (bf16 NHWC feat -> bf16 spp). 2 blocks per ROI
// (channel halves) = 512 blocks. SPP maxes of bf16 values are bf16-exact.
// ---------------------------------------------------------------------------
__global__ __launch_bounds__(256)
void k_roi_spp(const ushort* __restrict__ feat, const int* __restrict__ rois,
               ushort* __restrict__ spp)
{
    __shared__ float sm_blk[64 * 17];

    const int tid = threadIdx.x;
    const int roi = blockIdx.x >> 1;
    const int cg  = blockIdx.x & 1;

    const int bi = rois[roi * 5 + 0];
    int xm = (int)roundf((float)rois[roi * 5 + 1] * 0.25f);
    int ym = (int)roundf((float)rois[roi * 5 + 2] * 0.25f);
    xm = min(max(xm, 0), WFT - ROI_FT);
    ym = min(max(ym, 0), HFT - ROI_FT);

    const int cl = tid & 63;               // local channel 0..63
    const int by = tid >> 6;               // 0..3 (8-row band)
    const int c  = cg * 64 + cl;

    const ushort* base = feat + ((size_t)((bi * HFT + ym + by * 8)) * WFT + xm) * C2 + c;

    float mm[4];
    #pragma unroll
    for (int bx = 0; bx < 4; ++bx) mm[bx] = -INFINITY;

    for (int y = 0; y < 8; ++y) {
        const ushort* rowp = base + (size_t)y * (WFT * C2);
        #pragma unroll
        for (int bx = 0; bx < 4; ++bx)
            #pragma unroll
            for (int j = 0; j < 8; ++j)
                mm[bx] = fmaxf(mm[bx], bf2f(rowp[(bx * 8 + j) * C2]));
    }
    #pragma unroll
    for (int bx = 0; bx < 4; ++bx)
        sm_blk[cl * 17 + by * 4 + bx] = mm[bx];
    __syncthreads();

    if (tid < 64) {
        float v[16];
        #pragma unroll
        for (int k = 0; k < 16; ++k) v[k] = sm_blk[tid * 17 + k];
        ushort* o = spp + (size_t)roi * SPP_DIM;
        const int cc = cg * 64 + tid;
        #pragma unroll
        for (int k = 0; k < 16; ++k) o[640 + cc * 16 + k] = f2bf(v[k]);
        float g = -INFINITY;
        #pragma unroll
        for (int qy = 0; qy < 2; ++qy) {
            #pragma unroll
            for (int qx = 0; qx < 2; ++qx) {
                float q = fmaxf(fmaxf(v[(2 * qy) * 4 + 2 * qx],     v[(2 * qy) * 4 + 2 * qx + 1]),
                                fmaxf(v[(2 * qy + 1) * 4 + 2 * qx], v[(2 * qy + 1) * 4 + 2 * qx + 1]));
                o[128 + cc * 4 + qy * 2 + qx] = f2bf(q);
                g = fmaxf(g, q);
            }
        }
        o[cc] = f2bf(g);
    }
}

// ---------------------------------------------------------------------------
// Kernel D: FC1 via bf16 MFMA + bias + relu -> h bf16 [256][256].
// 1 wave/block computes 32 rows x 64 cols; K = 2688 (84 chunks). Grid 8x4.
// ---------------------------------------------------------------------------
__global__ __launch_bounds__(64)
void k_fc1(const ushort* __restrict__ spp, const ushort* __restrict__ f1T,
           const float* __restrict__ bias, ushort* __restrict__ h)
{
    const int m0 = blockIdx.x * 32;     // 8 blocks
    const int n0 = blockIdx.y * 64;     // 4 blocks
    const int l  = threadIdx.x;
    const int c16 = l & 15, hi = l >> 4;

    f32x4 acc[2][4] = {};
    for (int k0 = 0; k0 < SPP_DIM; k0 += 32) {
        short8 a[2], bb[4];
        #pragma unroll
        for (int fm = 0; fm < 2; ++fm)
            a[fm] = *(const short8*)(spp + (size_t)(m0 + fm * 16 + c16) * SPP_DIM + k0 + hi * 8);
        #pragma unroll
        for (int fn = 0; fn < 4; ++fn)
            bb[fn] = *(const short8*)(f1T + (size_t)(n0 + fn * 16 + c16) * SPP_DIM + k0 + hi * 8);
        #pragma unroll
        for (int fm = 0; fm < 2; ++fm)
            #pragma unroll
            for (int fn = 0; fn < 4; ++fn)
                acc[fm][fn] = __builtin_amdgcn_mfma_f32_16x16x32_bf16(
                    a[fm], bb[fn], acc[fm][fn], 0, 0, 0);
    }
    #pragma unroll
    for (int fn = 0; fn < 4; ++fn) {
        int col = n0 + fn * 16 + c16;
        float bv = bias[col];
        #pragma unroll
        for (int fm = 0; fm < 2; ++fm) {
            f32x4 a4 = acc[fm][fn];
            #pragma unroll
            for (int r = 0; r < 4; ++r) {
                int row = m0 + fm * 16 + hi * 4 + r;
                h[row * FC1_OUT + col] = f2bf(fmaxf(a4[r] + bv, 0.f));
            }
        }
    }
}

// ---------------------------------------------------------------------------
// Kernel E: FC2 via bf16 MFMA + bias -> out f32 [256][1000].
// 1 wave/block computes 32 rows x 64 cols; K = 256 (8 chunks). Grid 8x16.
// ---------------------------------------------------------------------------
__global__ __launch_bounds__(64)
void k_fc2(const ushort* __restrict__ h, const ushort* __restrict__ f2T,
           const float* __restrict__ bias, float* __restrict__ out)
{
    const int m0 = blockIdx.x * 32;     // 8 blocks
    const int n0 = blockIdx.y * 64;     // 16 blocks (N padded to 1024)
    const int l  = threadIdx.x;
    const int c16 = l & 15, hi = l >> 4;

    f32x4 acc[2][4] = {};
    #pragma unroll
    for (int k0 = 0; k0 < FC1_OUT; k0 += 32) {
        short8 a[2], bb[4];
        #pragma unroll
        for (int fm = 0; fm < 2; ++fm)
            a[fm] = *(const short8*)(h + (size_t)(m0 + fm * 16 + c16) * FC1_OUT + k0 + hi * 8);
        #pragma unroll
        for (int fn = 0; fn < 4; ++fn)
            bb[fn] = *(const short8*)(f2T + (size_t)(n0 + fn * 16 + c16) * FC1_OUT + k0 + hi * 8);
        #pragma unroll
        for (int fm = 0; fm < 2; ++fm)
            #pragma unroll
            for (int fn = 0; fn < 4; ++fn)
                acc[fm][fn] = __builtin_amdgcn_mfma_f32_16x16x32_bf16(
                    a[fm], bb[fn], acc[fm][fn], 0, 0, 0);
    }
    #pragma unroll
    for (int fn = 0; fn < 4; ++fn) {
        int col = n0 + fn * 16 + c16;
        if (col < NCLS) {
            float bv = bias[col];
            #pragma unroll
            for (int fm = 0; fm < 2; ++fm) {
                f32x4 a4 = acc[fm][fn];
                #pragma unroll
                for (int r = 0; r < 4; ++r) {
                    int row = m0 + fm * 16 + hi * 4 + r;
                    out[row * NCLS + col] = a4[r] + bv;
                }
            }
        }
    }
}

// ---------------------------------------------------------------------------
extern "C" void kernel_launch(void* const* d_in, const int* in_sizes, int n_in,
                              void* d_out, int out_size, void* d_ws, size_t ws_size,
                              hipStream_t stream)
{
    const float* x     = (const float*)d_in[0];
    const int*   rois  = (const int*)  d_in[1];
    const float* w1    = (const float*)d_in[2];
    const float* b1    = (const float*)d_in[3];
    const float* w2    = (const float*)d_in[4];
    const float* b2    = (const float*)d_in[5];
    const float* fc1_w = (const float*)d_in[6];
    const float* fc1_b = (const float*)d_in[7];
    const float* fc2_w = (const float*)d_in[8];
    const float* fc2_b = (const float*)d_in[9];
    float* out = (float*)d_out;

    // workspace (all bf16/ushort unless noted): mid | Wt | W1t | zp | feat |
    // spp | h | f1T | f2T   (~104 MB)
    ushort* midb  = (ushort*)d_ws;
    ushort* Wt    = midb  + (size_t)NB * HMID * WMID * C1;          // 33.55M
    ushort* W1t   = Wt    + 9 * 128 * 64;                           // 73728
    ushort* zp    = W1t   + 2048;                                   // 64
    ushort* featb = zp    + 64;
    ushort* sppb  = featb + (size_t)NB * HFT * WFT * C2;            // 16.78M
    ushort* hb    = sppb  + (size_t)NROIS * SPP_DIM;                // 688128
    ushort* f1T   = hb    + NROIS * FC1_OUT;                        // 65536
    ushort* f2T   = f1T   + (size_t)FC1_OUT * SPP_DIM;              // 688128

    k_w2t       <<<dim3(288),        256, 0, stream>>>(w2, Wt, zp);
    k_w1t       <<<dim3(8),          256, 0, stream>>>(w1, W1t);
    k_f1t       <<<dim3(42, 4),      256, 0, stream>>>(fc1_w, f1T);
    k_f2t       <<<dim3(4, 16),      256, 0, stream>>>(fc2_w, f2T);
    k_conv1_mfma<<<dim3(16, 64, NB), 512, 0, stream>>>(x, W1t, b1, midb);
    k_conv2_mfma<<<dim3(256),        512, 0, stream>>>(midb, Wt, b2, zp, featb);
    k_roi_spp   <<<dim3(NROIS * 2),  256, 0, stream>>>(featb, rois, sppb);
    k_fc1       <<<dim3(8, 4),       64,  0, stream>>>(sppb, f1T, fc1_b, hb);
    k_fc2       <<<dim3(8, 16),      64,  0, stream>>>(hb, f2T, fc2_b, out);
}

// Round 10
// 199.670 us; speedup vs baseline: 2.3413x; 2.3413x over previous
//
#include <hip/hip_runtime.h>
#include <math.h>

// ---- problem constants ----
#define NB      8
#define C_IN    3
#define HIMG    512
#define WIMG    512
#define C1      64      // conv1 out channels
#define HMID    256     // after pool1
#define WMID    256
#define C2      128     // conv2 out channels (C_FEAT)
#define HFT     128     // after pool2
#define WFT     128
#define NROIS   256
#define ROI_FT  32
#define SPP_DIM 2688    // 128*(1+4+16)
#define FC1_OUT 256
#define NCLS    1000

typedef unsigned short ushort;
typedef __attribute__((ext_vector_type(8))) short short8;
typedef __attribute__((ext_vector_type(4))) float f32x4;

#define GLOBAL_AS __attribute__((address_space(1)))
#define LDS_AS    __attribute__((address_space(3)))

static __device__ __forceinline__ ushort f2bf(float f) {
    unsigned u = __builtin_bit_cast(unsigned, f);
    unsigned r = (u + 0x7fffu + ((u >> 16) & 1u)) >> 16;   // RNE
    return (ushort)r;
}
static __device__ __forceinline__ float bf2f(ushort u) {
    return __builtin_bit_cast(float, (unsigned)u << 16);
}

// ---------------------------------------------------------------------------
// Kernel W2: w2 [oc][ci][3][3] f32 -> Wt2 [chunk18][oc128][cihalf32] bf16.
// chunk c = tap*2 + k0 (k0 = which 32-ci half). A B-load instruction then
// reads 16 consecutive oc x 64B = 1KB fully contiguous from L2.
// Also zeroes the 128B zero-page.
// ---------------------------------------------------------------------------
__global__ __launch_bounds__(256)
void k_w2t(const float* __restrict__ w2, ushort* __restrict__ Wt2,
           ushort* __restrict__ zp)
{
    int i = blockIdx.x * 256 + threadIdx.x;      // 18*128*32 = 73728
    if (blockIdx.x == 0 && threadIdx.x < 64) zp[threadIdx.x] = 0;
    if (i >= 73728) return;
    int c   = i >> 12;           // chunk 0..17
    int rem = i & 4095;
    int oc  = rem >> 5;
    int s   = rem & 31;
    int tap = c >> 1;
    int ci  = (c & 1) * 32 + s;
    Wt2[i] = f2bf(w2[(oc * 64 + ci) * 9 + tap]);
}

// ---------------------------------------------------------------------------
// Kernel W1: w1 [oc][ci][3][3] fp32 -> W1t [oc][k] bf16, k = tap*3+ci, pad 32
// ---------------------------------------------------------------------------
__global__ __launch_bounds__(256)
void k_w1t(const float* __restrict__ w1, ushort* __restrict__ W1t)
{
    int i = blockIdx.x * 256 + threadIdx.x;      // 64*32 = 2048
    if (i >= 2048) return;
    int oc = i >> 5, k = i & 31;
    float v = 0.f;
    if (k < 27) {
        int tap = k / 3, ci = k - 3 * tap;
        v = w1[oc * 27 + ci * 9 + tap];
    }
    W1t[i] = f2bf(v);
}

// ---------------------------------------------------------------------------
// Kernel F1T: fc1_w [2688][256] f32 -> f1T [256][2688] bf16 (LDS tile transp)
// ---------------------------------------------------------------------------
__global__ __launch_bounds__(256)
void k_f1t(const float* __restrict__ w, ushort* __restrict__ o)
{
    __shared__ float sm[64][65];
    const int k0 = blockIdx.x * 64;     // 42 blocks
    const int n0 = blockIdx.y * 64;     // 4 blocks
    #pragma unroll
    for (int s = 0; s < 16; ++s) {
        int idx = s * 256 + threadIdx.x;
        int lk = idx >> 6, ln = idx & 63;
        sm[lk][ln] = w[(size_t)(k0 + lk) * FC1_OUT + n0 + ln];
    }
    __syncthreads();
    #pragma unroll
    for (int s = 0; s < 16; ++s) {
        int idx = s * 256 + threadIdx.x;
        int ln = idx >> 6, lk = idx & 63;
        o[(size_t)(n0 + ln) * SPP_DIM + k0 + lk] = f2bf(sm[lk][ln]);
    }
}

// ---------------------------------------------------------------------------
// Kernel F2T: fc2_w [256][1000] f32 -> f2T [1024][256] bf16 (zero-padded rows)
// ---------------------------------------------------------------------------
__global__ __launch_bounds__(256)
void k_f2t(const float* __restrict__ w, ushort* __restrict__ o)
{
    __shared__ float sm[64][65];
    const int k0 = blockIdx.x * 64;     // 4 blocks
    const int n0 = blockIdx.y * 64;     // 16 blocks (cols padded to 1024)
    #pragma unroll
    for (int s = 0; s < 16; ++s) {
        int idx = s * 256 + threadIdx.x;
        int lk = idx >> 6, ln = idx & 63;
        sm[lk][ln] = (n0 + ln < NCLS) ? w[(size_t)(k0 + lk) * NCLS + n0 + ln] : 0.f;
    }
    __syncthreads();
    #pragma unroll
    for (int s = 0; s < 16; ++s) {
        int idx = s * 256 + threadIdx.x;
        int ln = idx >> 6, lk = idx & 63;
        o[(size_t)(n0 + ln) * FC1_OUT + k0 + lk] = f2bf(sm[lk][ln]);
    }
}

// ---------------------------------------------------------------------------
// Kernel A: conv1 via bf16 MFMA implicit GEMM + bias + relu + 2x2 pool.
// ---------------------------------------------------------------------------
__global__ __launch_bounds__(512, 4)
void k_conv1_mfma(const float* __restrict__ x, const ushort* __restrict__ W1t,
                  const float* __restrict__ b1, ushort* __restrict__ mid)
{
    __shared__ ushort sm_x[3 * 10 * 36 + 8];     // input tile, row stride 36
    __shared__ ushort sm_o[4 * 16 * 64];         // pooled out [py][px][oc] 8KB

    const int tid = threadIdx.x;
    const int tx = blockIdx.x;    // 0..15 (32 conv cols)
    const int ty = blockIdx.y;    // 0..63 (8 conv rows)
    const int b  = blockIdx.z;

    const int cy0 = ty * 8, cx0 = tx * 32;

    for (int t = tid; t < 3 * 10 * 34; t += 512) {
        int ci  = t / 340;
        int rem = t - ci * 340;
        int r = rem / 34, c = rem - r * 34;
        int gy = cy0 - 1 + r, gx = cx0 - 1 + c;
        float v = 0.f;
        if ((unsigned)gy < (unsigned)HIMG && (unsigned)gx < (unsigned)WIMG)
            v = x[((b * C_IN + ci) * HIMG + gy) * WIMG + gx];
        sm_x[ci * 360 + r * 36 + c] = f2bf(v);
    }
    __syncthreads();

    const int l   = tid & 63;
    const int wid = tid >> 6;
    const int wm  = wid & 3;       // conv-x offset wm*8
    const int wn  = wid >> 2;      // oc offset wn*32
    const int c16 = l & 15;
    const int hi  = l >> 4;
    const int ylane = (c16 >> 1) & 1;
    const int xlane = ((c16 >> 2) << 1) | (c16 & 1);
    const int xloc  = wm * 8 + xlane;

    int offj[8];
    #pragma unroll
    for (int j = 0; j < 8; ++j) {
        int k = hi * 8 + j;
        int tap = k / 3, ci = k - 3 * tap;
        int dy = tap / 3, dx = tap - 3 * dy;
        offj[j] = (k < 27) ? (ci * 360 + dy * 36 + dx) : 0;
    }

    short8 bf[2];
    #pragma unroll
    for (int fn = 0; fn < 2; ++fn)
        bf[fn] = *(const short8*)(W1t + (wn * 32 + fn * 16 + c16) * 32 + hi * 8);

    f32x4 acc[4][2] = {};
    #pragma unroll
    for (int fm = 0; fm < 4; ++fm) {
        int base = (2 * fm + ylane) * 36 + xloc;
        union { ushort u[8]; short8 s; } av;
        #pragma unroll
        for (int j = 0; j < 8; ++j) av.u[j] = sm_x[offj[j] + base];
        #pragma unroll
        for (int fn = 0; fn < 2; ++fn)
            acc[fm][fn] = __builtin_amdgcn_mfma_f32_16x16x32_bf16(
                av.s, bf[fn], acc[fm][fn], 0, 0, 0);
    }

    const int pxl = wm * 4 + hi;   // pooled px local 0..15
    #pragma unroll
    for (int fn = 0; fn < 2; ++fn) {
        int oc = wn * 32 + fn * 16 + c16;
        float bb = b1[oc];
        #pragma unroll
        for (int fm = 0; fm < 4; ++fm) {
            f32x4 a4 = acc[fm][fn];
            float m = fmaxf(fmaxf(a4[0], a4[1]), fmaxf(a4[2], a4[3]));
            sm_o[(fm * 16 + pxl) * 64 + oc] = f2bf(fmaxf(m + bb, 0.f));
        }
    }
    __syncthreads();
    {
        int row = tid >> 7;        // 0..3 local pooled row
        int off = tid & 127;       // 128 x 16B = 2KB per row
        uint4 v = *(const uint4*)(sm_o + row * (16 * 64) + off * 8);
        int py = ty * 4 + row;
        uint4* dst = (uint4*)(mid + ((size_t)(b * HMID + py) * WMID + tx * 16) * C1) + off;
        *dst = v;
    }
}

// ---------------------------------------------------------------------------
// Kernel B: conv2 bf16 MFMA (R7 structure + packed Wt2 B layout).
// 512 thr (8 waves: wm x4, wn x2), tile 8y x 32x, 128 oc, acc[4][4],
// __launch_bounds__(512,2). Staging via global_load_lds (pre-swizzled src).
// Dual register prefetch. B loads now 1KB-contiguous per instruction:
// addr = wlane + c*4096 + fn*512  (c = chunk index).
// ---------------------------------------------------------------------------
__global__ __launch_bounds__(512, 2)
void k_conv2_mfma(const ushort* __restrict__ mid, const ushort* __restrict__ Wt2,
                  const float* __restrict__ b2, const ushort* __restrict__ zp,
                  ushort* __restrict__ feat)
{
    __shared__ uint4 sm_in[512 * 6];   // 48KB; slots 0..2719 = 340 pos x 8 granules

    const int tid = threadIdx.x;
    const int tx = blockIdx.x;         // 0..7   (32 conv cols each)
    const int ty = blockIdx.y;         // 0..31  (8 conv rows each)
    const int b  = blockIdx.z;

    const int cy0 = ty * 8, cx0 = tx * 32;

    // ---- stage halo tile: async global->LDS, source pre-swizzled ----
    #pragma unroll
    for (int i = 0; i < 6; ++i) {
        int t   = i * 512 + tid;
        int pos = t >> 3, g = t & 7;
        int hy  = pos / 34, hx = pos - hy * 34;
        int gy  = cy0 - 1 + hy, gx = cx0 - 1 + hx;
        bool ok = (t < 2720) && ((unsigned)gy < (unsigned)HMID)
                             && ((unsigned)gx < (unsigned)WMID);
        const ushort* src = ok
            ? mid + (((size_t)(b * HMID + gy) * WMID + gx) * C1 + (g ^ (pos & 7)) * 8)
            : zp;
        __builtin_amdgcn_global_load_lds((const GLOBAL_AS void*)src,
                                         (LDS_AS void*)&sm_in[t], 16, 0, 0);
    }
    __syncthreads();

    // ---- wave / lane decomposition ----
    const int l   = tid & 63;
    const int wid = tid >> 6;
    const int wm  = wid & 3;        // x-offset wm*8
    const int wn  = wid >> 2;       // oc-offset wn*64
    const int c16 = l & 15;
    const int hi  = l >> 4;
    const int ylane = (c16 >> 1) & 1;
    const int xlane = ((c16 >> 2) << 1) | (c16 & 1);
    const int pos00 = ylane * 34 + wm * 8 + xlane;
    // per-lane B base in packed layout: [chunk][oc][32]
    const ushort* wlane = Wt2 + (wn * 64 + c16) * 32 + hi * 8;

    f32x4 acc[4][4] = {};
    short8 acur[4], anxt[4], bcur[4], bnxt[4];

    // chunk 0 (tap 0: dy=0,dx=0; k0=0)
    #pragma unroll
    for (int fm = 0; fm < 4; ++fm) {
        int pos = pos00 + fm * 68;
        acur[fm] = __builtin_bit_cast(short8, sm_in[pos * 8 + (hi ^ (pos & 7))]);
    }
    #pragma unroll
    for (int fn = 0; fn < 4; ++fn)
        bcur[fn] = *(const short8*)(wlane + fn * 512);

    #pragma unroll
    for (int c = 0; c < 18; ++c) {             // chunk: tap = c>>1, k0 = c&1
        const int cn   = (c < 17) ? c + 1 : 17;
        const int tapn = cn >> 1, k0n = cn & 1;
        const int dyn  = tapn / 3, dxn = tapn - 3 * dyn;
        #pragma unroll
        for (int fm = 0; fm < 4; ++fm) {       // prefetch next A (LDS)
            int pos = pos00 + dyn * 34 + dxn + fm * 68;
            int gi  = (hi + k0n * 4) ^ (pos & 7);
            anxt[fm] = __builtin_bit_cast(short8, sm_in[pos * 8 + gi]);
        }
        const ushort* wnp = wlane + cn * 4096;
        #pragma unroll
        for (int fn = 0; fn < 4; ++fn)         // prefetch next B (L2, 1KB dense)
            bnxt[fn] = *(const short8*)(wnp + fn * 512);

        __builtin_amdgcn_s_setprio(1);
        #pragma unroll
        for (int fm = 0; fm < 4; ++fm)
            #pragma unroll
            for (int fn = 0; fn < 4; ++fn)
                acc[fm][fn] = __builtin_amdgcn_mfma_f32_16x16x32_bf16(
                    acur[fm], bcur[fn], acc[fm][fn], 0, 0, 0);
        __builtin_amdgcn_s_setprio(0);

        #pragma unroll
        for (int q = 0; q < 4; ++q) { acur[q] = anxt[q]; bcur[q] = bnxt[q]; }
    }

    // ---- epilogue: pool 2x2 in-lane -> LDS [py][px][oc] -> linear stores ----
    __syncthreads();                       // all waves done reading sm_in
    ushort* sm_o = (ushort*)sm_in;         // reuse: 4*16*128*2B = 16KB
    const int pxl = wm * 4 + hi;
    #pragma unroll
    for (int fn = 0; fn < 4; ++fn) {
        int oc = wn * 64 + fn * 16 + c16;
        float bb = b2[oc];
        #pragma unroll
        for (int fm = 0; fm < 4; ++fm) {
            f32x4 a4 = acc[fm][fn];
            float m = fmaxf(fmaxf(a4[0], a4[1]), fmaxf(a4[2], a4[3]));
            sm_o[(fm * 16 + pxl) * 128 + oc] = f2bf(fmaxf(m + bb, 0.f));
        }
    }
    __syncthreads();
    const int py0 = ty * 4;
    #pragma unroll
    for (int pass = 0; pass < 2; ++pass) {
        int idx = pass * 512 + tid;        // 0..1023
        int row = idx >> 8;                // 0..3
        int off = idx & 255;               // 256 x 16B = 4KB per row
        uint4 v = *(const uint4*)(sm_o + row * (16 * 128) + off * 8);
        uint4* dst = (uint4*)(feat + ((size_t)(b * HFT + py0 + row) * WFT + tx * 16) * C2) + off;
        *dst = v;
    }
}

// ---------------------------------------------------------------------------
// Kernel C: ROI crop + SPP (bf16 NHWC feat -> bf16 spp). 2 blocks per ROI.
// ---------------------------------------------------------------------------
__global__ __launch_bounds__(256)
void k_roi_spp(const ushort* __restrict__ feat, const int* __restrict__ rois,
               ushort* __restrict__ spp)
{
    __shared__ float sm_blk[64 * 17];

    const int tid = threadIdx.x;
    const int roi = blockIdx.x >> 1;
    const int cg  = blockIdx.x & 1;

    const int bi = rois[roi * 5 + 0];
    int xm = (int)roundf((float)rois[roi * 5 + 1] * 0.25f);
    int ym = (int)roundf((float)rois[roi * 5 + 2] * 0.25f);
    xm = min(max(xm, 0), WFT - ROI_FT);
    ym = min(max(ym, 0), HFT - ROI_FT);

    const int cl = tid & 63;               // local channel 0..63
    const int by = tid >> 6;               // 0..3 (8-row band)
    const int c  = cg * 64 + cl;

    const ushort* base = feat + ((size_t)((bi * HFT + ym + by * 8)) * WFT + xm) * C2 + c;

    float mm[4];
    #pragma unroll
    for (int bx = 0; bx < 4; ++bx) mm[bx] = -INFINITY;

    for (int y = 0; y < 8; ++y) {
        const ushort* rowp = base + (size_t)y * (WFT * C2);
        #pragma unroll
        for (int bx = 0; bx < 4; ++bx)
            #pragma unroll
            for (int j = 0; j < 8; ++j)
                mm[bx] = fmaxf(mm[bx], bf2f(rowp[(bx * 8 + j) * C2]));
    }
    #pragma unroll
    for (int bx = 0; bx < 4; ++bx)
        sm_blk[cl * 17 + by * 4 + bx] = mm[bx];
    __syncthreads();

    if (tid < 64) {
        float v[16];
        #pragma unroll
        for (int k = 0; k < 16; ++k) v[k] = sm_blk[tid * 17 + k];
        ushort* o = spp + (size_t)roi * SPP_DIM;
        const int cc = cg * 64 + tid;
        #pragma unroll
        for (int k = 0; k < 16; ++k) o[640 + cc * 16 + k] = f2bf(v[k]);
        float g = -INFINITY;
        #pragma unroll
        for (int qy = 0; qy < 2; ++qy) {
            #pragma unroll
            for (int qx = 0; qx < 2; ++qx) {
                float q = fmaxf(fmaxf(v[(2 * qy) * 4 + 2 * qx],     v[(2 * qy) * 4 + 2 * qx + 1]),
                                fmaxf(v[(2 * qy + 1) * 4 + 2 * qx], v[(2 * qy + 1) * 4 + 2 * qx + 1]));
                o[128 + cc * 4 + qy * 2 + qx] = f2bf(q);
                g = fmaxf(g, q);
            }
        }
        o[cc] = f2bf(g);
    }
}

// ---------------------------------------------------------------------------
// Kernel D: FC1 via bf16 MFMA + bias + relu -> h bf16 [256][256].
// ---------------------------------------------------------------------------
__global__ __launch_bounds__(64)
void k_fc1(const ushort* __restrict__ spp, const ushort* __restrict__ f1T,
           const float* __restrict__ bias, ushort* __restrict__ h)
{
    const int m0 = blockIdx.x * 32;     // 8 blocks
    const int n0 = blockIdx.y * 64;     // 4 blocks
    const int l  = threadIdx.x;
    const int c16 = l & 15, hi = l >> 4;

    f32x4 acc[2][4] = {};
    for (int k0 = 0; k0 < SPP_DIM; k0 += 32) {
        short8 a[2], bb[4];
        #pragma unroll
        for (int fm = 0; fm < 2; ++fm)
            a[fm] = *(const short8*)(spp + (size_t)(m0 + fm * 16 + c16) * SPP_DIM + k0 + hi * 8);
        #pragma unroll
        for (int fn = 0; fn < 4; ++fn)
            bb[fn] = *(const short8*)(f1T + (size_t)(n0 + fn * 16 + c16) * SPP_DIM + k0 + hi * 8);
        #pragma unroll
        for (int fm = 0; fm < 2; ++fm)
            #pragma unroll
            for (int fn = 0; fn < 4; ++fn)
                acc[fm][fn] = __builtin_amdgcn_mfma_f32_16x16x32_bf16(
                    a[fm], bb[fn], acc[fm][fn], 0, 0, 0);
    }
    #pragma unroll
    for (int fn = 0; fn < 4; ++fn) {
        int col = n0 + fn * 16 + c16;
        float bv = bias[col];
        #pragma unroll
        for (int fm = 0; fm < 2; ++fm) {
            f32x4 a4 = acc[fm][fn];
            #pragma unroll
            for (int r = 0; r < 4; ++r) {
                int row = m0 + fm * 16 + hi * 4 + r;
                h[row * FC1_OUT + col] = f2bf(fmaxf(a4[r] + bv, 0.f));
            }
        }
    }
}

// ---------------------------------------------------------------------------
// Kernel E: FC2 via bf16 MFMA + bias -> out f32 [256][1000].
// ---------------------------------------------------------------------------
__global__ __launch_bounds__(64)
void k_fc2(const ushort* __restrict__ h, const ushort* __restrict__ f2T,
           const float* __restrict__ bias, float* __restrict__ out)
{
    const int m0 = blockIdx.x * 32;     // 8 blocks
    const int n0 = blockIdx.y * 64;     // 16 blocks (N padded to 1024)
    const int l  = threadIdx.x;
    const int c16 = l & 15, hi = l >> 4;

    f32x4 acc[2][4] = {};
    #pragma unroll
    for (int k0 = 0; k0 < FC1_OUT; k0 += 32) {
        short8 a[2], bb[4];
        #pragma unroll
        for (int fm = 0; fm < 2; ++fm)
            a[fm] = *(const short8*)(h + (size_t)(m0 + fm * 16 + c16) * FC1_OUT + k0 + hi * 8);
        #pragma unroll
        for (int fn = 0; fn < 4; ++fn)
            bb[fn] = *(const short8*)(f2T + (size_t)(n0 + fn * 16 + c16) * FC1_OUT + k0 + hi * 8);
        #pragma unroll
        for (int fm = 0; fm < 2; ++fm)
            #pragma unroll
            for (int fn = 0; fn < 4; ++fn)
                acc[fm][fn] = __builtin_amdgcn_mfma_f32_16x16x32_bf16(
                    a[fm], bb[fn], acc[fm][fn], 0, 0, 0);
    }
    #pragma unroll
    for (int fn = 0; fn < 4; ++fn) {
        int col = n0 + fn * 16 + c16;
        if (col < NCLS) {
            float bv = bias[col];
            #pragma unroll
            for (int fm = 0; fm < 2; ++fm) {
                f32x4 a4 = acc[fm][fn];
                #pragma unroll
                for (int r = 0; r < 4; ++r) {
                    int row = m0 + fm * 16 + hi * 4 + r;
                    out[row * NCLS + col] = a4[r] + bv;
                }
            }
        }
    }
}

// ---------------------------------------------------------------------------
extern "C" void kernel_launch(void* const* d_in, const int* in_sizes, int n_in,
                              void* d_out, int out_size, void* d_ws, size_t ws_size,
                              hipStream_t stream)
{
    const float* x     = (const float*)d_in[0];
    const int*   rois  = (const int*)  d_in[1];
    const float* w1    = (const float*)d_in[2];
    const float* b1    = (const float*)d_in[3];
    const float* w2    = (const float*)d_in[4];
    const float* b2    = (const float*)d_in[5];
    const float* fc1_w = (const float*)d_in[6];
    const float* fc1_b = (const float*)d_in[7];
    const float* fc2_w = (const float*)d_in[8];
    const float* fc2_b = (const float*)d_in[9];
    float* out = (float*)d_out;

    // workspace: mid | Wt2 | W1t | zp | feat | spp | h | f1T | f2T
    ushort* midb  = (ushort*)d_ws;
    ushort* Wt2   = midb  + (size_t)NB * HMID * WMID * C1;          // 33.55M
    ushort* W1t   = Wt2   + 73728;
    ushort* zp    = W1t   + 2048;                                   // 64
    ushort* featb = zp    + 64;
    ushort* sppb  = featb + (size_t)NB * HFT * WFT * C2;            // 16.78M
    ushort* hb    = sppb  + (size_t)NROIS * SPP_DIM;                // 688128
    ushort* f1T   = hb    + NROIS * FC1_OUT;                        // 65536
    ushort* f2T   = f1T   + (size_t)FC1_OUT * SPP_DIM;              // 688128

    k_w2t       <<<dim3(288),        256, 0, stream>>>(w2, Wt2, zp);
    k_w1t       <<<dim3(8),          256, 0, stream>>>(w1, W1t);
    k_f1t       <<<dim3(42, 4),      256, 0, stream>>>(fc1_w, f1T);
    k_f2t       <<<dim3(4, 16),      256, 0, stream>>>(fc2_w, f2T);
    k_conv1_mfma<<<dim3(16, 64, NB), 512, 0, stream>>>(x, W1t, b1, midb);
    k_conv2_mfma<<<dim3(8, 32, NB),  512, 0, stream>>>(midb, Wt2, b2, zp, featb);
    k_roi_spp   <<<dim3(NROIS * 2),  256, 0, stream>>>(featb, rois, sppb);
    k_fc1       <<<dim3(8, 4),       64,  0, stream>>>(sppb, f1T, fc1_b, hb);
    k_fc2       <<<dim3(8, 16),      64,  0, stream>>>(hb, f2T, fc2_b, out);
}

// Round 11
// 173.752 us; speedup vs baseline: 2.6906x; 1.1492x over previous
//
#include <hip/hip_runtime.h>
#include <math.h>

// ---- problem constants ----
#define NB      8
#define C_IN    3
#define HIMG    512
#define WIMG    512
#define C1      64      // conv1 out channels
#define HMID    256     // after pool1
#define WMID    256
#define C2      128     // conv2 out channels (C_FEAT)
#define HFT     128     // after pool2
#define WFT     128
#define NROIS   256
#define ROI_FT  32
#define SPP_DIM 2688    // 128*(1+4+16)
#define FC1_OUT 256
#define NCLS    1000

typedef unsigned short ushort;
typedef __attribute__((ext_vector_type(8))) short short8;
typedef __attribute__((ext_vector_type(4))) float f32x4;

#define GLOBAL_AS __attribute__((address_space(1)))
#define LDS_AS    __attribute__((address_space(3)))

static __device__ __forceinline__ ushort f2bf(float f) {
    unsigned u = __builtin_bit_cast(unsigned, f);
    unsigned r = (u + 0x7fffu + ((u >> 16) & 1u)) >> 16;   // RNE
    return (ushort)r;
}
static __device__ __forceinline__ float bf2f(ushort u) {
    return __builtin_bit_cast(float, (unsigned)u << 16);
}

// ---------------------------------------------------------------------------
// Kernel P: fused weight prep (one launch instead of 4).
//  blocks [0,288)   : w2 -> Wt2 [chunk18][oc128][cihalf32] bf16 (+ zero-page)
//  blocks [288,296) : w1 -> W1t [oc][k32] bf16 (k = tap*3+ci, zero-padded)
//  blocks [296,464) : fc1_w [2688][256] -> f1T [256][2688] bf16 (tile transp)
//  blocks [464,528) : fc2_w [256][1000] -> f2T [1024][256] bf16 (padded)
// ---------------------------------------------------------------------------
__global__ __launch_bounds__(256)
void k_prep(const float* __restrict__ w2, const float* __restrict__ w1,
            const float* __restrict__ fc1w, const float* __restrict__ fc2w,
            ushort* __restrict__ Wt2, ushort* __restrict__ W1t,
            ushort* __restrict__ zp, ushort* __restrict__ f1T,
            ushort* __restrict__ f2T)
{
    __shared__ float sm[64][65];
    const int bx = blockIdx.x;
    const int tid = threadIdx.x;

    if (bx < 288) {                              // ---- w2t ----
        if (bx == 0 && tid < 64) zp[tid] = 0;
        int i = bx * 256 + tid;                  // 18*128*32 = 73728
        if (i < 73728) {
            int c   = i >> 12;
            int rem = i & 4095;
            int oc  = rem >> 5;
            int s   = rem & 31;
            int tap = c >> 1;
            int ci  = (c & 1) * 32 + s;
            Wt2[i] = f2bf(w2[(oc * 64 + ci) * 9 + tap]);
        }
    } else if (bx < 296) {                       // ---- w1t ----
        int i = (bx - 288) * 256 + tid;          // 2048
        if (i < 2048) {
            int oc = i >> 5, k = i & 31;
            float v = 0.f;
            if (k < 27) {
                int tap = k / 3, ci = k - 3 * tap;
                v = w1[oc * 27 + ci * 9 + tap];
            }
            W1t[i] = f2bf(v);
        }
    } else if (bx < 464) {                       // ---- f1t ----
        int j  = bx - 296;                       // 0..167 (42 x 4)
        int k0 = (j % 42) * 64;
        int n0 = (j / 42) * 64;
        #pragma unroll
        for (int s = 0; s < 16; ++s) {
            int idx = s * 256 + tid;
            int lk = idx >> 6, ln = idx & 63;
            sm[lk][ln] = fc1w[(size_t)(k0 + lk) * FC1_OUT + n0 + ln];
        }
        __syncthreads();
        #pragma unroll
        for (int s = 0; s < 16; ++s) {
            int idx = s * 256 + tid;
            int ln = idx >> 6, lk = idx & 63;
            f1T[(size_t)(n0 + ln) * SPP_DIM + k0 + lk] = f2bf(sm[lk][ln]);
        }
    } else {                                     // ---- f2t ----
        int j  = bx - 464;                       // 0..63 (4 x 16)
        int k0 = (j & 3) * 64;
        int n0 = (j >> 2) * 64;
        #pragma unroll
        for (int s = 0; s < 16; ++s) {
            int idx = s * 256 + tid;
            int lk = idx >> 6, ln = idx & 63;
            sm[lk][ln] = (n0 + ln < NCLS) ? fc2w[(size_t)(k0 + lk) * NCLS + n0 + ln] : 0.f;
        }
        __syncthreads();
        #pragma unroll
        for (int s = 0; s < 16; ++s) {
            int idx = s * 256 + tid;
            int ln = idx >> 6, lk = idx & 63;
            f2T[(size_t)(n0 + ln) * FC1_OUT + k0 + lk] = f2bf(sm[lk][ln]);
        }
    }
}

// ---------------------------------------------------------------------------
// Kernel A: conv1 bf16 MFMA + bias + relu + 2x2 pool, 4 y-subtiles per block.
// Block: 512 thr, conv tile 32y x 32x (4 subtiles of 8y), all 64 oc.
// One 3x34x34 halo stage + one weight load amortized over 4 subtiles.
// ---------------------------------------------------------------------------
__global__ __launch_bounds__(512, 4)
void k_conv1_mfma(const float* __restrict__ x, const ushort* __restrict__ W1t,
                  const float* __restrict__ b1, ushort* __restrict__ mid)
{
    __shared__ ushort sm_x[3 * 34 * 36 + 8];     // 34 rows x stride 36 x 3 ci
    __shared__ ushort sm_o[4 * 16 * 64];         // pooled out [py][px][oc] 8KB

    const int tid = threadIdx.x;
    const int tx = blockIdx.x;    // 0..15 (32 conv cols)
    const int TY = blockIdx.y;    // 0..15 (32 conv rows = 4 subtiles)
    const int b  = blockIdx.z;

    const int cy0 = TY * 32, cx0 = tx * 32;

    // stage input halo 3 x 34 x 34 fp32 -> bf16 (rows cy0-1 .. cy0+32)
    for (int t = tid; t < 3 * 34 * 34; t += 512) {
        int ci  = t / 1156;
        int rem = t - ci * 1156;
        int r = rem / 34, c = rem - r * 34;
        int gy = cy0 - 1 + r, gx = cx0 - 1 + c;
        float v = 0.f;
        if ((unsigned)gy < (unsigned)HIMG && (unsigned)gx < (unsigned)WIMG)
            v = x[((b * C_IN + ci) * HIMG + gy) * WIMG + gx];
        sm_x[ci * 1224 + r * 36 + c] = f2bf(v);
    }
    __syncthreads();

    const int l   = tid & 63;
    const int wid = tid >> 6;
    const int wm  = wid & 3;       // conv-x offset wm*8
    const int wn  = wid >> 2;      // oc offset wn*32
    const int c16 = l & 15;
    const int hi  = l >> 4;
    const int ylane = (c16 >> 1) & 1;
    const int xlane = ((c16 >> 2) << 1) | (c16 & 1);
    const int xloc  = wm * 8 + xlane;

    int offj[8];
    #pragma unroll
    for (int j = 0; j < 8; ++j) {
        int k = hi * 8 + j;
        int tap = k / 3, ci = k - 3 * tap;
        int dy = tap / 3, dx = tap - 3 * dy;
        offj[j] = (k < 27) ? (ci * 1224 + dy * 36 + dx) : 0;
    }

    short8 bf[2];
    #pragma unroll
    for (int fn = 0; fn < 2; ++fn)
        bf[fn] = *(const short8*)(W1t + (wn * 32 + fn * 16 + c16) * 32 + hi * 8);

    const int pxl = wm * 4 + hi;   // pooled px local 0..15
    float bb0 = b1[wn * 32 + c16];
    float bb1 = b1[wn * 32 + 16 + c16];

    for (int s = 0; s < 4; ++s) {
        f32x4 acc[4][2] = {};
        #pragma unroll
        for (int fm = 0; fm < 4; ++fm) {
            int base = (s * 8 + 2 * fm + ylane) * 36 + xloc;
            union { ushort u[8]; short8 v; } av;
            #pragma unroll
            for (int j = 0; j < 8; ++j) av.u[j] = sm_x[offj[j] + base];
            #pragma unroll
            for (int fn = 0; fn < 2; ++fn)
                acc[fm][fn] = __builtin_amdgcn_mfma_f32_16x16x32_bf16(
                    av.v, bf[fn], acc[fm][fn], 0, 0, 0);
        }

        #pragma unroll
        for (int fn = 0; fn < 2; ++fn) {
            int oc = wn * 32 + fn * 16 + c16;
            float bb = fn ? bb1 : bb0;
            #pragma unroll
            for (int fm = 0; fm < 4; ++fm) {
                f32x4 a4 = acc[fm][fn];
                float m = fmaxf(fmaxf(a4[0], a4[1]), fmaxf(a4[2], a4[3]));
                sm_o[(fm * 16 + pxl) * 64 + oc] = f2bf(fmaxf(m + bb, 0.f));
            }
        }
        __syncthreads();
        {
            int row = tid >> 7;        // 0..3 local pooled row
            int off = tid & 127;       // 128 x 16B = 2KB per row
            uint4 v = *(const uint4*)(sm_o + row * (16 * 64) + off * 8);
            int py = TY * 16 + s * 4 + row;
            uint4* dst = (uint4*)(mid + ((size_t)(b * HMID + py) * WMID + tx * 16) * C1) + off;
            *dst = v;
        }
        __syncthreads();               // sm_o free for next subtile
    }
}

// ---------------------------------------------------------------------------
// Kernel B: conv2 bf16 MFMA (R10 structure, unchanged — 98us, MfmaUtil 33%).
// ---------------------------------------------------------------------------
__global__ __launch_bounds__(512, 2)
void k_conv2_mfma(const ushort* __restrict__ mid, const ushort* __restrict__ Wt2,
                  const float* __restrict__ b2, const ushort* __restrict__ zp,
                  ushort* __restrict__ feat)
{
    __shared__ uint4 sm_in[512 * 6];   // 48KB; slots 0..2719 = 340 pos x 8 granules

    const int tid = threadIdx.x;
    const int tx = blockIdx.x;         // 0..7   (32 conv cols each)
    const int ty = blockIdx.y;         // 0..31  (8 conv rows each)
    const int b  = blockIdx.z;

    const int cy0 = ty * 8, cx0 = tx * 32;

    // ---- stage halo tile: async global->LDS, source pre-swizzled ----
    #pragma unroll
    for (int i = 0; i < 6; ++i) {
        int t   = i * 512 + tid;
        int pos = t >> 3, g = t & 7;
        int hy  = pos / 34, hx = pos - hy * 34;
        int gy  = cy0 - 1 + hy, gx = cx0 - 1 + hx;
        bool ok = (t < 2720) && ((unsigned)gy < (unsigned)HMID)
                             && ((unsigned)gx < (unsigned)WMID);
        const ushort* src = ok
            ? mid + (((size_t)(b * HMID + gy) * WMID + gx) * C1 + (g ^ (pos & 7)) * 8)
            : zp;
        __builtin_amdgcn_global_load_lds((const GLOBAL_AS void*)src,
                                         (LDS_AS void*)&sm_in[t], 16, 0, 0);
    }
    __syncthreads();

    // ---- wave / lane decomposition ----
    const int l   = tid & 63;
    const int wid = tid >> 6;
    const int wm  = wid & 3;        // x-offset wm*8
    const int wn  = wid >> 2;       // oc-offset wn*64
    const int c16 = l & 15;
    const int hi  = l >> 4;
    const int ylane = (c16 >> 1) & 1;
    const int xlane = ((c16 >> 2) << 1) | (c16 & 1);
    const int pos00 = ylane * 34 + wm * 8 + xlane;
    const ushort* wlane = Wt2 + (wn * 64 + c16) * 32 + hi * 8;

    f32x4 acc[4][4] = {};
    short8 acur[4], anxt[4], bcur[4], bnxt[4];

    #pragma unroll
    for (int fm = 0; fm < 4; ++fm) {
        int pos = pos00 + fm * 68;
        acur[fm] = __builtin_bit_cast(short8, sm_in[pos * 8 + (hi ^ (pos & 7))]);
    }
    #pragma unroll
    for (int fn = 0; fn < 4; ++fn)
        bcur[fn] = *(const short8*)(wlane + fn * 512);

    #pragma unroll
    for (int c = 0; c < 18; ++c) {             // chunk: tap = c>>1, k0 = c&1
        const int cn   = (c < 17) ? c + 1 : 17;
        const int tapn = cn >> 1, k0n = cn & 1;
        const int dyn  = tapn / 3, dxn = tapn - 3 * dyn;
        #pragma unroll
        for (int fm = 0; fm < 4; ++fm) {       // prefetch next A (LDS)
            int pos = pos00 + dyn * 34 + dxn + fm * 68;
            int gi  = (hi + k0n * 4) ^ (pos & 7);
            anxt[fm] = __builtin_bit_cast(short8, sm_in[pos * 8 + gi]);
        }
        const ushort* wnp = wlane + cn * 4096;
        #pragma unroll
        for (int fn = 0; fn < 4; ++fn)         // prefetch next B (L2, 1KB dense)
            bnxt[fn] = *(const short8*)(wnp + fn * 512);

        __builtin_amdgcn_s_setprio(1);
        #pragma unroll
        for (int fm = 0; fm < 4; ++fm)
            #pragma unroll
            for (int fn = 0; fn < 4; ++fn)
                acc[fm][fn] = __builtin_amdgcn_mfma_f32_16x16x32_bf16(
                    acur[fm], bcur[fn], acc[fm][fn], 0, 0, 0);
        __builtin_amdgcn_s_setprio(0);

        #pragma unroll
        for (int q = 0; q < 4; ++q) { acur[q] = anxt[q]; bcur[q] = bnxt[q]; }
    }

    // ---- epilogue: pool 2x2 in-lane -> LDS [py][px][oc] -> linear stores ----
    __syncthreads();                       // all waves done reading sm_in
    ushort* sm_o = (ushort*)sm_in;         // reuse: 4*16*128*2B = 16KB
    const int pxl = wm * 4 + hi;
    #pragma unroll
    for (int fn = 0; fn < 4; ++fn) {
        int oc = wn * 64 + fn * 16 + c16;
        float bb = b2[oc];
        #pragma unroll
        for (int fm = 0; fm < 4; ++fm) {
            f32x4 a4 = acc[fm][fn];
            float m = fmaxf(fmaxf(a4[0], a4[1]), fmaxf(a4[2], a4[3]));
            sm_o[(fm * 16 + pxl) * 128 + oc] = f2bf(fmaxf(m + bb, 0.f));
        }
    }
    __syncthreads();
    const int py0 = ty * 4;
    #pragma unroll
    for (int pass = 0; pass < 2; ++pass) {
        int idx = pass * 512 + tid;        // 0..1023
        int row = idx >> 8;                // 0..3
        int off = idx & 255;               // 256 x 16B = 4KB per row
        uint4 v = *(const uint4*)(sm_o + row * (16 * 128) + off * 8);
        uint4* dst = (uint4*)(feat + ((size_t)(b * HFT + py0 + row) * WFT + tx * 16) * C2) + off;
        *dst = v;
    }
}

// ---------------------------------------------------------------------------
// Kernel C: ROI crop + SPP (bf16 NHWC feat -> bf16 spp). 2 blocks per ROI
// (channel halves). uint loads = 2 channels per lane (half the load count).
// tid: cl = tid&31 (ch-pair), sub = tid>>5: by = sub>>1 (8x8 band),
// hf = sub&1 (4-row half of band).
// ---------------------------------------------------------------------------
__global__ __launch_bounds__(256)
void k_roi_spp(const ushort* __restrict__ feat, const int* __restrict__ rois,
               ushort* __restrict__ spp)
{
    __shared__ float sm_f[64 * 32];        // [lc][by][bx][hf] = 64x4x4x2

    const int tid = threadIdx.x;
    const int roi = blockIdx.x >> 1;
    const int cg  = blockIdx.x & 1;

    const int bi = rois[roi * 5 + 0];
    int xm = (int)roundf((float)rois[roi * 5 + 1] * 0.25f);
    int ym = (int)roundf((float)rois[roi * 5 + 2] * 0.25f);
    xm = min(max(xm, 0), WFT - ROI_FT);
    ym = min(max(ym, 0), HFT - ROI_FT);

    const int cl  = tid & 31;              // ch-pair within 64-ch half
    const int sub = tid >> 5;              // 0..7
    const int by  = sub >> 1;              // 0..3
    const int hf  = sub & 1;               // 0..1
    const int c0  = cg * 64 + cl * 2;

    const ushort* base = feat
        + ((size_t)((bi * HFT + ym + by * 8 + hf * 4)) * WFT + xm) * C2 + c0;

    float mm[4][2];
    #pragma unroll
    for (int bx = 0; bx < 4; ++bx) { mm[bx][0] = -INFINITY; mm[bx][1] = -INFINITY; }

    #pragma unroll
    for (int y = 0; y < 4; ++y) {
        const ushort* rowp = base + (size_t)y * (WFT * C2);
        #pragma unroll
        for (int bx = 0; bx < 4; ++bx)
            #pragma unroll
            for (int j = 0; j < 8; ++j) {
                unsigned v = *(const unsigned*)(rowp + (bx * 8 + j) * C2);
                mm[bx][0] = fmaxf(mm[bx][0], __builtin_bit_cast(float, v << 16));
                mm[bx][1] = fmaxf(mm[bx][1], __builtin_bit_cast(float, v & 0xffff0000u));
            }
    }
    #pragma unroll
    for (int bx = 0; bx < 4; ++bx) {
        sm_f[((cl * 2) * 4 + by) * 8 + bx * 2 + hf]     = mm[bx][0];
        sm_f[((cl * 2 + 1) * 4 + by) * 8 + bx * 2 + hf] = mm[bx][1];
    }
    __syncthreads();

    if (tid < 64) {
        float v[16];
        #pragma unroll
        for (int by2 = 0; by2 < 4; ++by2)
            #pragma unroll
            for (int bx = 0; bx < 4; ++bx)
                v[by2 * 4 + bx] = fmaxf(sm_f[(tid * 4 + by2) * 8 + bx * 2],
                                        sm_f[(tid * 4 + by2) * 8 + bx * 2 + 1]);
        ushort* o = spp + (size_t)roi * SPP_DIM;
        const int cc = cg * 64 + tid;
        #pragma unroll
        for (int k = 0; k < 16; ++k) o[640 + cc * 16 + k] = f2bf(v[k]);
        float g = -INFINITY;
        #pragma unroll
        for (int qy = 0; qy < 2; ++qy) {
            #pragma unroll
            for (int qx = 0; qx < 2; ++qx) {
                float q = fmaxf(fmaxf(v[(2 * qy) * 4 + 2 * qx],     v[(2 * qy) * 4 + 2 * qx + 1]),
                                fmaxf(v[(2 * qy + 1) * 4 + 2 * qx], v[(2 * qy + 1) * 4 + 2 * qx + 1]));
                o[128 + cc * 4 + qy * 2 + qx] = f2bf(q);
                g = fmaxf(g, q);
            }
        }
        o[cc] = f2bf(g);
    }
}

// ---------------------------------------------------------------------------
// Kernel D: FC1 via bf16 MFMA + bias + relu -> h bf16 [256][256].
// Register double-buffered K-loop (84 chunks) — hides L2 latency.
// ---------------------------------------------------------------------------
__global__ __launch_bounds__(64)
void k_fc1(const ushort* __restrict__ spp, const ushort* __restrict__ f1T,
           const float* __restrict__ bias, ushort* __restrict__ h)
{
    const int m0 = blockIdx.x * 32;     // 8 blocks
    const int n0 = blockIdx.y * 64;     // 4 blocks
    const int l  = threadIdx.x;
    const int c16 = l & 15, hi = l >> 4;

    const ushort* ap0 = spp + (size_t)(m0 + c16) * SPP_DIM + hi * 8;
    const ushort* ap1 = ap0 + 16 * SPP_DIM;
    const ushort* bp[4];
    #pragma unroll
    for (int fn = 0; fn < 4; ++fn)
        bp[fn] = f1T + (size_t)(n0 + fn * 16 + c16) * SPP_DIM + hi * 8;

    f32x4 acc[2][4] = {};
    short8 a[2], bb[4], an[2], bn[4];
    a[0] = *(const short8*)(ap0);
    a[1] = *(const short8*)(ap1);
    #pragma unroll
    for (int fn = 0; fn < 4; ++fn) bb[fn] = *(const short8*)(bp[fn]);

    for (int k0 = 0; k0 < SPP_DIM; k0 += 32) {
        int kn = (k0 + 32 < SPP_DIM) ? k0 + 32 : k0;
        an[0] = *(const short8*)(ap0 + kn);
        an[1] = *(const short8*)(ap1 + kn);
        #pragma unroll
        for (int fn = 0; fn < 4; ++fn) bn[fn] = *(const short8*)(bp[fn] + kn);
        #pragma unroll
        for (int fm = 0; fm < 2; ++fm)
            #pragma unroll
            for (int fn = 0; fn < 4; ++fn)
                acc[fm][fn] = __builtin_amdgcn_mfma_f32_16x16x32_bf16(
                    a[fm], bb[fn], acc[fm][fn], 0, 0, 0);
        a[0] = an[0]; a[1] = an[1];
        #pragma unroll
        for (int fn = 0; fn < 4; ++fn) bb[fn] = bn[fn];
    }
    #pragma unroll
    for (int fn = 0; fn < 4; ++fn) {
        int col = n0 + fn * 16 + c16;
        float bv = bias[col];
        #pragma unroll
        for (int fm = 0; fm < 2; ++fm) {
            f32x4 a4 = acc[fm][fn];
            #pragma unroll
            for (int r = 0; r < 4; ++r) {
                int row = m0 + fm * 16 + hi * 4 + r;
                h[row * FC1_OUT + col] = f2bf(fmaxf(a4[r] + bv, 0.f));
            }
        }
    }
}

// ---------------------------------------------------------------------------
// Kernel E: FC2 via bf16 MFMA + bias -> out f32 [256][1000].
// ---------------------------------------------------------------------------
__global__ __launch_bounds__(64)
void k_fc2(const ushort* __restrict__ h, const ushort* __restrict__ f2T,
           const float* __restrict__ bias, float* __restrict__ out)
{
    const int m0 = blockIdx.x * 32;     // 8 blocks
    const int n0 = blockIdx.y * 64;     // 16 blocks (N padded to 1024)
    const int l  = threadIdx.x;
    const int c16 = l & 15, hi = l >> 4;

    f32x4 acc[2][4] = {};
    #pragma unroll
    for (int k0 = 0; k0 < FC1_OUT; k0 += 32) {
        short8 a[2], bb[4];
        #pragma unroll
        for (int fm = 0; fm < 2; ++fm)
            a[fm] = *(const short8*)(h + (size_t)(m0 + fm * 16 + c16) * FC1_OUT + k0 + hi * 8);
        #pragma unroll
        for (int fn = 0; fn < 4; ++fn)
            bb[fn] = *(const short8*)(f2T + (size_t)(n0 + fn * 16 + c16) * FC1_OUT + k0 + hi * 8);
        #pragma unroll
        for (int fm = 0; fm < 2; ++fm)
            #pragma unroll
            for (int fn = 0; fn < 4; ++fn)
                acc[fm][fn] = __builtin_amdgcn_mfma_f32_16x16x32_bf16(
                    a[fm], bb[fn], acc[fm][fn], 0, 0, 0);
    }
    #pragma unroll
    for (int fn = 0; fn < 4; ++fn) {
        int col = n0 + fn * 16 + c16;
        if (col < NCLS) {
            float bv = bias[col];
            #pragma unroll
            for (int fm = 0; fm < 2; ++fm) {
                f32x4 a4 = acc[fm][fn];
                #pragma unroll
                for (int r = 0; r < 4; ++r) {
                    int row = m0 + fm * 16 + hi * 4 + r;
                    out[row * NCLS + col] = a4[r] + bv;
                }
            }
        }
    }
}

// ---------------------------------------------------------------------------
extern "C" void kernel_launch(void* const* d_in, const int* in_sizes, int n_in,
                              void* d_out, int out_size, void* d_ws, size_t ws_size,
                              hipStream_t stream)
{
    const float* x     = (const float*)d_in[0];
    const int*   rois  = (const int*)  d_in[1];
    const float* w1    = (const float*)d_in[2];
    const float* b1    = (const float*)d_in[3];
    const float* w2    = (const float*)d_in[4];
    const float* b2    = (const float*)d_in[5];
    const float* fc1_w = (const float*)d_in[6];
    const float* fc1_b = (const float*)d_in[7];
    const float* fc2_w = (const float*)d_in[8];
    const float* fc2_b = (const float*)d_in[9];
    float* out = (float*)d_out;

    // workspace: mid | Wt2 | W1t | zp | feat | spp | h | f1T | f2T
    ushort* midb  = (ushort*)d_ws;
    ushort* Wt2   = midb  + (size_t)NB * HMID * WMID * C1;          // 33.55M
    ushort* W1t   = Wt2   + 73728;
    ushort* zp    = W1t   + 2048;                                   // 64
    ushort* featb = zp    + 64;
    ushort* sppb  = featb + (size_t)NB * HFT * WFT * C2;            // 16.78M
    ushort* hb    = sppb  + (size_t)NROIS * SPP_DIM;                // 688128
    ushort* f1T   = hb    + NROIS * FC1_OUT;                        // 65536
    ushort* f2T   = f1T   + (size_t)FC1_OUT * SPP_DIM;              // 688128

    k_prep      <<<dim3(528),        256, 0, stream>>>(w2, w1, fc1_w, fc2_w,
                                                       Wt2, W1t, zp, f1T, f2T);
    k_conv1_mfma<<<dim3(16, 16, NB), 512, 0, stream>>>(x, W1t, b1, midb);
    k_conv2_mfma<<<dim3(8, 32, NB),  512, 0, stream>>>(midb, Wt2, b2, zp, featb);
    k_roi_spp   <<<dim3(NROIS * 2),  256, 0, stream>>>(featb, rois, sppb);
    k_fc1       <<<dim3(8, 4),       64,  0, stream>>>(sppb, f1T, fc1_b, hb);
    k_fc2       <<<dim3(8, 16),      64,  0, stream>>>(hb, f2T, fc2_b, out);
}

// Round 12
// 170.970 us; speedup vs baseline: 2.7344x; 1.0163x over previous
//
#include <hip/hip_runtime.h>
#include <math.h>

// ---- problem constants ----
#define NB      8
#define C_IN    3
#define HIMG    512
#define WIMG    512
#define C1      64      // conv1 out channels
#define HMID    256     // after pool1
#define WMID    256
#define C2      128     // conv2 out channels (C_FEAT)
#define HFT     128     // after pool2
#define WFT     128
#define NROIS   256
#define ROI_FT  32
#define SPP_DIM 2688    // 128*(1+4+16)
#define FC1_OUT 256
#define NCLS    1000

typedef unsigned short ushort;
typedef __attribute__((ext_vector_type(8))) short short8;
typedef __attribute__((ext_vector_type(4))) float f32x4;

#define GLOBAL_AS __attribute__((address_space(1)))
#define LDS_AS    __attribute__((address_space(3)))

static __device__ __forceinline__ ushort f2bf(float f) {
    unsigned u = __builtin_bit_cast(unsigned, f);
    unsigned r = (u + 0x7fffu + ((u >> 16) & 1u)) >> 16;   // RNE
    return (ushort)r;
}
static __device__ __forceinline__ float bf2f(ushort u) {
    return __builtin_bit_cast(float, (unsigned)u << 16);
}

// ---------------------------------------------------------------------------
// Kernel A+P: conv1 bf16 MFMA (z<8) fused with weight prep (z>=8).
// Prep pids: [0,144) w2->Wt2 | [144,312) fc1T | [312,376) fc2T.
// conv1 builds its own weight fragments from w1 directly (no W1t dependency
// inside this dispatch — avoids intra-kernel race).
// ---------------------------------------------------------------------------
__global__ __launch_bounds__(512, 4)
void k_conv1_prep(const float* __restrict__ x, const float* __restrict__ w1,
                  const float* __restrict__ b1, ushort* __restrict__ mid,
                  const float* __restrict__ w2, const float* __restrict__ fc1w,
                  const float* __restrict__ fc2w, ushort* __restrict__ Wt2,
                  ushort* __restrict__ zp, ushort* __restrict__ f1T,
                  ushort* __restrict__ f2T)
{
    __shared__ ushort sm_x[3 * 34 * 36 + 8];     // conv1: 34 rows x 36 x 3 ci
    __shared__ ushort sm_o[4 * 16 * 64];         // conv1: pooled out 8KB
    __shared__ float  sm_t[64][65];              // prep: transpose tile 16.6KB

    const int tid = threadIdx.x;

    if (blockIdx.z >= 8) {                       // ================ PREP ====
        int pid = (blockIdx.z - 8) * 256 + blockIdx.y * 16 + blockIdx.x;
        if (pid >= 376) return;
        if (pid < 144) {                         // ---- w2 -> Wt2 ----
            if (pid == 0 && tid < 64) zp[tid] = 0;
            int i = pid * 512 + tid;             // 73728 = 144*512
            int c   = i >> 12;
            int rem = i & 4095;
            int oc  = rem >> 5;
            int s   = rem & 31;
            int tap = c >> 1;
            int ci  = (c & 1) * 32 + s;
            Wt2[i] = f2bf(w2[(oc * 64 + ci) * 9 + tap]);
        } else if (pid < 312) {                  // ---- fc1_w transpose ----
            int j  = pid - 144;                  // 0..167 (42 x 4)
            int k0 = (j % 42) * 64;
            int n0 = (j / 42) * 64;
            #pragma unroll
            for (int s = 0; s < 8; ++s) {
                int idx = s * 512 + tid;
                int lk = idx >> 6, ln = idx & 63;
                sm_t[lk][ln] = fc1w[(size_t)(k0 + lk) * FC1_OUT + n0 + ln];
            }
            __syncthreads();
            #pragma unroll
            for (int s = 0; s < 8; ++s) {
                int idx = s * 512 + tid;
                int ln = idx >> 6, lk = idx & 63;
                f1T[(size_t)(n0 + ln) * SPP_DIM + k0 + lk] = f2bf(sm_t[lk][ln]);
            }
        } else {                                 // ---- fc2_w transpose ----
            int j  = pid - 312;                  // 0..63 (4 x 16)
            int k0 = (j & 3) * 64;
            int n0 = (j >> 2) * 64;
            #pragma unroll
            for (int s = 0; s < 8; ++s) {
                int idx = s * 512 + tid;
                int lk = idx >> 6, ln = idx & 63;
                sm_t[lk][ln] = (n0 + ln < NCLS) ? fc2w[(size_t)(k0 + lk) * NCLS + n0 + ln] : 0.f;
            }
            __syncthreads();
            #pragma unroll
            for (int s = 0; s < 8; ++s) {
                int idx = s * 512 + tid;
                int ln = idx >> 6, lk = idx & 63;
                f2T[(size_t)(n0 + ln) * FC1_OUT + k0 + lk] = f2bf(sm_t[lk][ln]);
            }
        }
        return;
    }

    // ================ CONV1 (4 y-subtiles per block) ====
    const int tx = blockIdx.x;    // 0..15 (32 conv cols)
    const int TY = blockIdx.y;    // 0..15 (32 conv rows = 4 subtiles)
    const int b  = blockIdx.z;

    const int cy0 = TY * 32, cx0 = tx * 32;

    for (int t = tid; t < 3 * 34 * 34; t += 512) {
        int ci  = t / 1156;
        int rem = t - ci * 1156;
        int r = rem / 34, c = rem - r * 34;
        int gy = cy0 - 1 + r, gx = cx0 - 1 + c;
        float v = 0.f;
        if ((unsigned)gy < (unsigned)HIMG && (unsigned)gx < (unsigned)WIMG)
            v = x[((b * C_IN + ci) * HIMG + gy) * WIMG + gx];
        sm_x[ci * 1224 + r * 36 + c] = f2bf(v);
    }

    const int l   = tid & 63;
    const int wid = tid >> 6;
    const int wm  = wid & 3;       // conv-x offset wm*8
    const int wn  = wid >> 2;      // oc offset wn*32
    const int c16 = l & 15;
    const int hi  = l >> 4;
    const int ylane = (c16 >> 1) & 1;
    const int xlane = ((c16 >> 2) << 1) | (c16 & 1);
    const int xloc  = wm * 8 + xlane;

    int offj[8];
    #pragma unroll
    for (int j = 0; j < 8; ++j) {
        int k = hi * 8 + j;
        int tap = k / 3, ci = k - 3 * tap;
        int dy = tap / 3, dx = tap - 3 * dy;
        offj[j] = (k < 27) ? (ci * 1224 + dy * 36 + dx) : 0;
    }

    // weight fragments straight from w1 (fp32, L2-hot): k = hi*8+j -> tap,ci
    short8 bf[2];
    #pragma unroll
    for (int fn = 0; fn < 2; ++fn) {
        int oc = wn * 32 + fn * 16 + c16;
        union { ushort u[8]; short8 v; } wv;
        #pragma unroll
        for (int j = 0; j < 8; ++j) {
            int k = hi * 8 + j;
            float w = 0.f;
            if (k < 27) {
                int tap = k / 3, ci = k - 3 * tap;
                w = w1[oc * 27 + ci * 9 + tap];
            }
            wv.u[j] = f2bf(w);
        }
        bf[fn] = wv.v;
    }
    __syncthreads();               // sm_x staged (overlaps weight gather)

    const int pxl = wm * 4 + hi;   // pooled px local 0..15
    float bb0 = b1[wn * 32 + c16];
    float bb1 = b1[wn * 32 + 16 + c16];

    for (int s = 0; s < 4; ++s) {
        f32x4 acc[4][2] = {};
        #pragma unroll
        for (int fm = 0; fm < 4; ++fm) {
            int base = (s * 8 + 2 * fm + ylane) * 36 + xloc;
            union { ushort u[8]; short8 v; } av;
            #pragma unroll
            for (int j = 0; j < 8; ++j) av.u[j] = sm_x[offj[j] + base];
            #pragma unroll
            for (int fn = 0; fn < 2; ++fn)
                acc[fm][fn] = __builtin_amdgcn_mfma_f32_16x16x32_bf16(
                    av.v, bf[fn], acc[fm][fn], 0, 0, 0);
        }

        #pragma unroll
        for (int fn = 0; fn < 2; ++fn) {
            int oc = wn * 32 + fn * 16 + c16;
            float bb = fn ? bb1 : bb0;
            #pragma unroll
            for (int fm = 0; fm < 4; ++fm) {
                f32x4 a4 = acc[fm][fn];
                float m = fmaxf(fmaxf(a4[0], a4[1]), fmaxf(a4[2], a4[3]));
                sm_o[(fm * 16 + pxl) * 64 + oc] = f2bf(fmaxf(m + bb, 0.f));
            }
        }
        __syncthreads();
        {
            int row = tid >> 7;        // 0..3 local pooled row
            int off = tid & 127;       // 128 x 16B = 2KB per row
            uint4 v = *(const uint4*)(sm_o + row * (16 * 64) + off * 8);
            int py = TY * 16 + s * 4 + row;
            uint4* dst = (uint4*)(mid + ((size_t)(b * HMID + py) * WMID + tx * 16) * C1) + off;
            *dst = v;
        }
        __syncthreads();               // sm_o free for next subtile
    }
}

// ---------------------------------------------------------------------------
// Kernel B: conv2 bf16 MFMA (R10 structure + 2-deep B prefetch).
// B-L2 latency (~300-400cy) > 1 chunk of MFMA issue at 2 waves/SIMD — rotate
// b0/b1/bn so chunk c+2's loads are in flight during chunk c's MFMAs.
// ---------------------------------------------------------------------------
__global__ __launch_bounds__(512, 2)
void k_conv2_mfma(const ushort* __restrict__ mid, const ushort* __restrict__ Wt2,
                  const float* __restrict__ b2, const ushort* __restrict__ zp,
                  ushort* __restrict__ feat)
{
    __shared__ uint4 sm_in[512 * 6];   // 48KB; slots 0..2719 = 340 pos x 8 granules

    const int tid = threadIdx.x;
    const int tx = blockIdx.x;         // 0..7   (32 conv cols each)
    const int ty = blockIdx.y;         // 0..31  (8 conv rows each)
    const int b  = blockIdx.z;

    const int cy0 = ty * 8, cx0 = tx * 32;

    // ---- stage halo tile: async global->LDS, source pre-swizzled ----
    #pragma unroll
    for (int i = 0; i < 6; ++i) {
        int t   = i * 512 + tid;
        int pos = t >> 3, g = t & 7;
        int hy  = pos / 34, hx = pos - hy * 34;
        int gy  = cy0 - 1 + hy, gx = cx0 - 1 + hx;
        bool ok = (t < 2720) && ((unsigned)gy < (unsigned)HMID)
                             && ((unsigned)gx < (unsigned)WMID);
        const ushort* src = ok
            ? mid + (((size_t)(b * HMID + gy) * WMID + gx) * C1 + (g ^ (pos & 7)) * 8)
            : zp;
        __builtin_amdgcn_global_load_lds((const GLOBAL_AS void*)src,
                                         (LDS_AS void*)&sm_in[t], 16, 0, 0);
    }
    __syncthreads();

    // ---- wave / lane decomposition ----
    const int l   = tid & 63;
    const int wid = tid >> 6;
    const int wm  = wid & 3;        // x-offset wm*8
    const int wn  = wid >> 2;       // oc-offset wn*64
    const int c16 = l & 15;
    const int hi  = l >> 4;
    const int ylane = (c16 >> 1) & 1;
    const int xlane = ((c16 >> 2) << 1) | (c16 & 1);
    const int pos00 = ylane * 34 + wm * 8 + xlane;
    const ushort* wlane = Wt2 + (wn * 64 + c16) * 32 + hi * 8;

    f32x4 acc[4][4] = {};
    short8 acur[4], anxt[4], b0[4], b1r[4], bn[4];

    // prologue: A chunk 0; B chunks 0 and 1
    #pragma unroll
    for (int fm = 0; fm < 4; ++fm) {
        int pos = pos00 + fm * 68;
        acur[fm] = __builtin_bit_cast(short8, sm_in[pos * 8 + (hi ^ (pos & 7))]);
    }
    #pragma unroll
    for (int fn = 0; fn < 4; ++fn) {
        b0[fn]  = *(const short8*)(wlane + fn * 512);
        b1r[fn] = *(const short8*)(wlane + 4096 + fn * 512);
    }

    #pragma unroll
    for (int c = 0; c < 18; ++c) {             // chunk: tap = c>>1, k0 = c&1
        const int cn2 = (c < 16) ? c + 2 : 17;
        const ushort* wnp = wlane + cn2 * 4096;
        #pragma unroll
        for (int fn = 0; fn < 4; ++fn)         // prefetch B, 2 chunks ahead
            bn[fn] = *(const short8*)(wnp + fn * 512);

        const int cn   = (c < 17) ? c + 1 : 17;
        const int tapn = cn >> 1, k0n = cn & 1;
        const int dyn  = tapn / 3, dxn = tapn - 3 * dyn;
        #pragma unroll
        for (int fm = 0; fm < 4; ++fm) {       // prefetch A, 1 chunk ahead (LDS)
            int pos = pos00 + dyn * 34 + dxn + fm * 68;
            int gi  = (hi + k0n * 4) ^ (pos & 7);
            anxt[fm] = __builtin_bit_cast(short8, sm_in[pos * 8 + gi]);
        }

        __builtin_amdgcn_s_setprio(1);
        #pragma unroll
        for (int fm = 0; fm < 4; ++fm)
            #pragma unroll
            for (int fn = 0; fn < 4; ++fn)
                acc[fm][fn] = __builtin_amdgcn_mfma_f32_16x16x32_bf16(
                    acur[fm], b0[fn], acc[fm][fn], 0, 0, 0);
        __builtin_amdgcn_s_setprio(0);

        #pragma unroll
        for (int q = 0; q < 4; ++q) {
            acur[q] = anxt[q]; b0[q] = b1r[q]; b1r[q] = bn[q];
        }
    }

    // ---- epilogue: pool 2x2 in-lane -> LDS [py][px][oc] -> linear stores ----
    __syncthreads();                       // all waves done reading sm_in
    ushort* sm_o = (ushort*)sm_in;         // reuse: 4*16*128*2B = 16KB
    const int pxl = wm * 4 + hi;
    #pragma unroll
    for (int fn = 0; fn < 4; ++fn) {
        int oc = wn * 64 + fn * 16 + c16;
        float bb = b2[oc];
        #pragma unroll
        for (int fm = 0; fm < 4; ++fm) {
            f32x4 a4 = acc[fm][fn];
            float m = fmaxf(fmaxf(a4[0], a4[1]), fmaxf(a4[2], a4[3]));
            sm_o[(fm * 16 + pxl) * 128 + oc] = f2bf(fmaxf(m + bb, 0.f));
        }
    }
    __syncthreads();
    const int py0 = ty * 4;
    #pragma unroll
    for (int pass = 0; pass < 2; ++pass) {
        int idx = pass * 512 + tid;        // 0..1023
        int row = idx >> 8;                // 0..3
        int off = idx & 255;               // 256 x 16B = 4KB per row
        uint4 v = *(const uint4*)(sm_o + row * (16 * 128) + off * 8);
        uint4* dst = (uint4*)(feat + ((size_t)(b * HFT + py0 + row) * WFT + tx * 16) * C2) + off;
        *dst = v;
    }
}

// ---------------------------------------------------------------------------
// Kernel C: ROI crop + SPP (bf16 NHWC feat -> bf16 spp). 2 blocks per ROI.
// ---------------------------------------------------------------------------
__global__ __launch_bounds__(256)
void k_roi_spp(const ushort* __restrict__ feat, const int* __restrict__ rois,
               ushort* __restrict__ spp)
{
    __shared__ float sm_f[64 * 32];        // [lc][by][bx][hf] = 64x4x4x2

    const int tid = threadIdx.x;
    const int roi = blockIdx.x >> 1;
    const int cg  = blockIdx.x & 1;

    const int bi = rois[roi * 5 + 0];
    int xm = (int)roundf((float)rois[roi * 5 + 1] * 0.25f);
    int ym = (int)roundf((float)rois[roi * 5 + 2] * 0.25f);
    xm = min(max(xm, 0), WFT - ROI_FT);
    ym = min(max(ym, 0), HFT - ROI_FT);

    const int cl  = tid & 31;              // ch-pair within 64-ch half
    const int sub = tid >> 5;              // 0..7
    const int by  = sub >> 1;              // 0..3
    const int hf  = sub & 1;               // 0..1
    const int c0  = cg * 64 + cl * 2;

    const ushort* base = feat
        + ((size_t)((bi * HFT + ym + by * 8 + hf * 4)) * WFT + xm) * C2 + c0;

    float mm[4][2];
    #pragma unroll
    for (int bx = 0; bx < 4; ++bx) { mm[bx][0] = -INFINITY; mm[bx][1] = -INFINITY; }

    #pragma unroll
    for (int y = 0; y < 4; ++y) {
        const ushort* rowp = base + (size_t)y * (WFT * C2);
        #pragma unroll
        for (int bx = 0; bx < 4; ++bx)
            #pragma unroll
            for (int j = 0; j < 8; ++j) {
                unsigned v = *(const unsigned*)(rowp + (bx * 8 + j) * C2);
                mm[bx][0] = fmaxf(mm[bx][0], __builtin_bit_cast(float, v << 16));
                mm[bx][1] = fmaxf(mm[bx][1], __builtin_bit_cast(float, v & 0xffff0000u));
            }
    }
    #pragma unroll
    for (int bx = 0; bx < 4; ++bx) {
        sm_f[((cl * 2) * 4 + by) * 8 + bx * 2 + hf]     = mm[bx][0];
        sm_f[((cl * 2 + 1) * 4 + by) * 8 + bx * 2 + hf] = mm[bx][1];
    }
    __syncthreads();

    if (tid < 64) {
        float v[16];
        #pragma unroll
        for (int by2 = 0; by2 < 4; ++by2)
            #pragma unroll
            for (int bx = 0; bx < 4; ++bx)
                v[by2 * 4 + bx] = fmaxf(sm_f[(tid * 4 + by2) * 8 + bx * 2],
                                        sm_f[(tid * 4 + by2) * 8 + bx * 2 + 1]);
        ushort* o = spp + (size_t)roi * SPP_DIM;
        const int cc = cg * 64 + tid;
        #pragma unroll
        for (int k = 0; k < 16; ++k) o[640 + cc * 16 + k] = f2bf(v[k]);
        float g = -INFINITY;
        #pragma unroll
        for (int qy = 0; qy < 2; ++qy) {
            #pragma unroll
            for (int qx = 0; qx < 2; ++qx) {
                float q = fmaxf(fmaxf(v[(2 * qy) * 4 + 2 * qx],     v[(2 * qy) * 4 + 2 * qx + 1]),
                                fmaxf(v[(2 * qy + 1) * 4 + 2 * qx], v[(2 * qy + 1) * 4 + 2 * qx + 1]));
                o[128 + cc * 4 + qy * 2 + qx] = f2bf(q);
                g = fmaxf(g, q);
            }
        }
        o[cc] = f2bf(g);
    }
}

// ---------------------------------------------------------------------------
// Kernel D: FC1 via bf16 MFMA + bias + relu -> h bf16 [256][256].
// ---------------------------------------------------------------------------
__global__ __launch_bounds__(64)
void k_fc1(const ushort* __restrict__ spp, const ushort* __restrict__ f1T,
           const float* __restrict__ bias, ushort* __restrict__ h)
{
    const int m0 = blockIdx.x * 32;     // 8 blocks
    const int n0 = blockIdx.y * 64;     // 4 blocks
    const int l  = threadIdx.x;
    const int c16 = l & 15, hi = l >> 4;

    const ushort* ap0 = spp + (size_t)(m0 + c16) * SPP_DIM + hi * 8;
    const ushort* ap1 = ap0 + 16 * SPP_DIM;
    const ushort* bp[4];
    #pragma unroll
    for (int fn = 0; fn < 4; ++fn)
        bp[fn] = f1T + (size_t)(n0 + fn * 16 + c16) * SPP_DIM + hi * 8;

    f32x4 acc[2][4] = {};
    short8 a[2], bb[4], an[2], bn[4];
    a[0] = *(const short8*)(ap0);
    a[1] = *(const short8*)(ap1);
    #pragma unroll
    for (int fn = 0; fn < 4; ++fn) bb[fn] = *(const short8*)(bp[fn]);

    for (int k0 = 0; k0 < SPP_DIM; k0 += 32) {
        int kn = (k0 + 32 < SPP_DIM) ? k0 + 32 : k0;
        an[0] = *(const short8*)(ap0 + kn);
        an[1] = *(const short8*)(ap1 + kn);
        #pragma unroll
        for (int fn = 0; fn < 4; ++fn) bn[fn] = *(const short8*)(bp[fn] + kn);
        #pragma unroll
        for (int fm = 0; fm < 2; ++fm)
            #pragma unroll
            for (int fn = 0; fn < 4; ++fn)
                acc[fm][fn] = __builtin_amdgcn_mfma_f32_16x16x32_bf16(
                    a[fm], bb[fn], acc[fm][fn], 0, 0, 0);
        a[0] = an[0]; a[1] = an[1];
        #pragma unroll
        for (int fn = 0; fn < 4; ++fn) bb[fn] = bn[fn];
    }
    #pragma unroll
    for (int fn = 0; fn < 4; ++fn) {
        int col = n0 + fn * 16 + c16;
        float bv = bias[col];
        #pragma unroll
        for (int fm = 0; fm < 2; ++fm) {
            f32x4 a4 = acc[fm][fn];
            #pragma unroll
            for (int r = 0; r < 4; ++r) {
                int row = m0 + fm * 16 + hi * 4 + r;
                h[row * FC1_OUT + col] = f2bf(fmaxf(a4[r] + bv, 0.f));
            }
        }
    }
}

// ---------------------------------------------------------------------------
// Kernel E: FC2 via bf16 MFMA + bias -> out f32 [256][1000].
// ---------------------------------------------------------------------------
__global__ __launch_bounds__(64)
void k_fc2(const ushort* __restrict__ h, const ushort* __restrict__ f2T,
           const float* __restrict__ bias, float* __restrict__ out)
{
    const int m0 = blockIdx.x * 32;     // 8 blocks
    const int n0 = blockIdx.y * 64;     // 16 blocks (N padded to 1024)
    const int l  = threadIdx.x;
    const int c16 = l & 15, hi = l >> 4;

    f32x4 acc[2][4] = {};
    #pragma unroll
    for (int k0 = 0; k0 < FC1_OUT; k0 += 32) {
        short8 a[2], bb[4];
        #pragma unroll
        for (int fm = 0; fm < 2; ++fm)
            a[fm] = *(const short8*)(h + (size_t)(m0 + fm * 16 + c16) * FC1_OUT + k0 + hi * 8);
        #pragma unroll
        for (int fn = 0; fn < 4; ++fn)
            bb[fn] = *(const short8*)(f2T + (size_t)(n0 + fn * 16 + c16) * FC1_OUT + k0 + hi * 8);
        #pragma unroll
        for (int fm = 0; fm < 2; ++fm)
            #pragma unroll
            for (int fn = 0; fn < 4; ++fn)
                acc[fm][fn] = __builtin_amdgcn_mfma_f32_16x16x32_bf16(
                    a[fm], bb[fn], acc[fm][fn], 0, 0, 0);
    }
    #pragma unroll
    for (int fn = 0; fn < 4; ++fn) {
        int col = n0 + fn * 16 + c16;
        if (col < NCLS) {
            float bv = bias[col];
            #pragma unroll
            for (int fm = 0; fm < 2; ++fm) {
                f32x4 a4 = acc[fm][fn];
                #pragma unroll
                for (int r = 0; r < 4; ++r) {
                    int row = m0 + fm * 16 + hi * 4 + r;
                    out[row * NCLS + col] = a4[r] + bv;
                }
            }
        }
    }
}

// ---------------------------------------------------------------------------
extern "C" void kernel_launch(void* const* d_in, const int* in_sizes, int n_in,
                              void* d_out, int out_size, void* d_ws, size_t ws_size,
                              hipStream_t stream)
{
    const float* x     = (const float*)d_in[0];
    const int*   rois  = (const int*)  d_in[1];
    const float* w1    = (const float*)d_in[2];
    const float* b1    = (const float*)d_in[3];
    const float* w2    = (const float*)d_in[4];
    const float* b2    = (const float*)d_in[5];
    const float* fc1_w = (const float*)d_in[6];
    const float* fc1_b = (const float*)d_in[7];
    const float* fc2_w = (const float*)d_in[8];
    const float* fc2_b = (const float*)d_in[9];
    float* out = (float*)d_out;

    // workspace: mid | Wt2 | zp | feat | spp | h | f1T | f2T
    ushort* midb  = (ushort*)d_ws;
    ushort* Wt2   = midb  + (size_t)NB * HMID * WMID * C1;          // 33.55M
    ushort* zp    = Wt2   + 73728;                                  // 64
    ushort* featb = zp    + 64;
    ushort* sppb  = featb + (size_t)NB * HFT * WFT * C2;            // 16.78M
    ushort* hb    = sppb  + (size_t)NROIS * SPP_DIM;                // 688128
    ushort* f1T   = hb    + NROIS * FC1_OUT;                        // 65536
    ushort* f2T   = f1T   + (size_t)FC1_OUT * SPP_DIM;              // 688128

    k_conv1_prep<<<dim3(16, 16, 10), 512, 0, stream>>>(
        x, w1, b1, midb, w2, fc1_w, fc2_w, Wt2, zp, f1T, f2T);
    k_conv2_mfma<<<dim3(8, 32, NB),  512, 0, stream>>>(midb, Wt2, b2, zp, featb);
    k_roi_spp   <<<dim3(NROIS * 2),  256, 0, stream>>>(featb, rois, sppb);
    k_fc1       <<<dim3(8, 4),       64,  0, stream>>>(sppb, f1T, fc1_b, hb);
    k_fc2       <<<dim3(8, 16),      64,  0, stream>>>(hb, f2T, fc2_b, out);
}

// Round 13
// 158.323 us; speedup vs baseline: 2.9528x; 1.0799x over previous
//
#include <hip/hip_runtime.h>
#include <math.h>

// ---- problem constants ----
#define NB      8
#define C_IN    3
#define HIMG    512
#define WIMG    512
#define C1      64      // conv1 out channels
#define HMID    256     // after pool1
#define WMID    256
#define C2      128     // conv2 out channels (C_FEAT)
#define HFT     128     // after pool2
#define WFT     128
#define NROIS   256
#define ROI_FT  32
#define SPP_DIM 2688    // 128*(1+4+16)
#define FC1_OUT 256
#define NCLS    1000

typedef unsigned short ushort;
typedef __attribute__((ext_vector_type(8))) short short8;
typedef __attribute__((ext_vector_type(4))) float f32x4;

#define GLOBAL_AS __attribute__((address_space(1)))
#define LDS_AS    __attribute__((address_space(3)))

static __device__ __forceinline__ ushort f2bf(float f) {
    unsigned u = __builtin_bit_cast(unsigned, f);
    unsigned r = (u + 0x7fffu + ((u >> 16) & 1u)) >> 16;   // RNE
    return (ushort)r;
}
static __device__ __forceinline__ float bf2f(ushort u) {
    return __builtin_bit_cast(float, (unsigned)u << 16);
}

// ---------------------------------------------------------------------------
// Kernel A+P: conv1 bf16 MFMA (z<8) fused with weight prep (z>=8).
// Prep pids: [0,144) w2->Wt2 | [144,312) fc1T | [312,376) fc2T.
// conv1 builds its own weight fragments from w1 directly (no intra-dispatch
// dependency).  [byte-identical to R12]
// ---------------------------------------------------------------------------
__global__ __launch_bounds__(512, 4)
void k_conv1_prep(const float* __restrict__ x, const float* __restrict__ w1,
                  const float* __restrict__ b1, ushort* __restrict__ mid,
                  const float* __restrict__ w2, const float* __restrict__ fc1w,
                  const float* __restrict__ fc2w, ushort* __restrict__ Wt2,
                  ushort* __restrict__ zp, ushort* __restrict__ f1T,
                  ushort* __restrict__ f2T)
{
    __shared__ ushort sm_x[3 * 34 * 36 + 8];     // conv1: 34 rows x 36 x 3 ci
    __shared__ ushort sm_o[4 * 16 * 64];         // conv1: pooled out 8KB
    __shared__ float  sm_t[64][65];              // prep: transpose tile 16.6KB

    const int tid = threadIdx.x;

    if (blockIdx.z >= 8) {                       // ================ PREP ====
        int pid = (blockIdx.z - 8) * 256 + blockIdx.y * 16 + blockIdx.x;
        if (pid >= 376) return;
        if (pid < 144) {                         // ---- w2 -> Wt2 ----
            if (pid == 0 && tid < 64) zp[tid] = 0;
            int i = pid * 512 + tid;             // 73728 = 144*512
            int c   = i >> 12;
            int rem = i & 4095;
            int oc  = rem >> 5;
            int s   = rem & 31;
            int tap = c >> 1;
            int ci  = (c & 1) * 32 + s;
            Wt2[i] = f2bf(w2[(oc * 64 + ci) * 9 + tap]);
        } else if (pid < 312) {                  // ---- fc1_w transpose ----
            int j  = pid - 144;                  // 0..167 (42 x 4)
            int k0 = (j % 42) * 64;
            int n0 = (j / 42) * 64;
            #pragma unroll
            for (int s = 0; s < 8; ++s) {
                int idx = s * 512 + tid;
                int lk = idx >> 6, ln = idx & 63;
                sm_t[lk][ln] = fc1w[(size_t)(k0 + lk) * FC1_OUT + n0 + ln];
            }
            __syncthreads();
            #pragma unroll
            for (int s = 0; s < 8; ++s) {
                int idx = s * 512 + tid;
                int ln = idx >> 6, lk = idx & 63;
                f1T[(size_t)(n0 + ln) * SPP_DIM + k0 + lk] = f2bf(sm_t[lk][ln]);
            }
        } else {                                 // ---- fc2_w transpose ----
            int j  = pid - 312;                  // 0..63 (4 x 16)
            int k0 = (j & 3) * 64;
            int n0 = (j >> 2) * 64;
            #pragma unroll
            for (int s = 0; s < 8; ++s) {
                int idx = s * 512 + tid;
                int lk = idx >> 6, ln = idx & 63;
                sm_t[lk][ln] = (n0 + ln < NCLS) ? fc2w[(size_t)(k0 + lk) * NCLS + n0 + ln] : 0.f;
            }
            __syncthreads();
            #pragma unroll
            for (int s = 0; s < 8; ++s) {
                int idx = s * 512 + tid;
                int ln = idx >> 6, lk = idx & 63;
                f2T[(size_t)(n0 + ln) * FC1_OUT + k0 + lk] = f2bf(sm_t[lk][ln]);
            }
        }
        return;
    }

    // ================ CONV1 (4 y-subtiles per block) ====
    const int tx = blockIdx.x;    // 0..15 (32 conv cols)
    const int TY = blockIdx.y;    // 0..15 (32 conv rows = 4 subtiles)
    const int b  = blockIdx.z;

    const int cy0 = TY * 32, cx0 = tx * 32;

    for (int t = tid; t < 3 * 34 * 34; t += 512) {
        int ci  = t / 1156;
        int rem = t - ci * 1156;
        int r = rem / 34, c = rem - r * 34;
        int gy = cy0 - 1 + r, gx = cx0 - 1 + c;
        float v = 0.f;
        if ((unsigned)gy < (unsigned)HIMG && (unsigned)gx < (unsigned)WIMG)
            v = x[((b * C_IN + ci) * HIMG + gy) * WIMG + gx];
        sm_x[ci * 1224 + r * 36 + c] = f2bf(v);
    }

    const int l   = tid & 63;
    const int wid = tid >> 6;
    const int wm  = wid & 3;       // conv-x offset wm*8
    const int wn  = wid >> 2;      // oc offset wn*32
    const int c16 = l & 15;
    const int hi  = l >> 4;
    const int ylane = (c16 >> 1) & 1;
    const int xlane = ((c16 >> 2) << 1) | (c16 & 1);
    const int xloc  = wm * 8 + xlane;

    int offj[8];
    #pragma unroll
    for (int j = 0; j < 8; ++j) {
        int k = hi * 8 + j;
        int tap = k / 3, ci = k - 3 * tap;
        int dy = tap / 3, dx = tap - 3 * dy;
        offj[j] = (k < 27) ? (ci * 1224 + dy * 36 + dx) : 0;
    }

    // weight fragments straight from w1 (fp32, L2-hot): k = hi*8+j -> tap,ci
    short8 bf[2];
    #pragma unroll
    for (int fn = 0; fn < 2; ++fn) {
        int oc = wn * 32 + fn * 16 + c16;
        union { ushort u[8]; short8 v; } wv;
        #pragma unroll
        for (int j = 0; j < 8; ++j) {
            int k = hi * 8 + j;
            float w = 0.f;
            if (k < 27) {
                int tap = k / 3, ci = k - 3 * tap;
                w = w1[oc * 27 + ci * 9 + tap];
            }
            wv.u[j] = f2bf(w);
        }
        bf[fn] = wv.v;
    }
    __syncthreads();               // sm_x staged (overlaps weight gather)

    const int pxl = wm * 4 + hi;   // pooled px local 0..15
    float bb0 = b1[wn * 32 + c16];
    float bb1 = b1[wn * 32 + 16 + c16];

    for (int s = 0; s < 4; ++s) {
        f32x4 acc[4][2] = {};
        #pragma unroll
        for (int fm = 0; fm < 4; ++fm) {
            int base = (s * 8 + 2 * fm + ylane) * 36 + xloc;
            union { ushort u[8]; short8 v; } av;
            #pragma unroll
            for (int j = 0; j < 8; ++j) av.u[j] = sm_x[offj[j] + base];
            #pragma unroll
            for (int fn = 0; fn < 2; ++fn)
                acc[fm][fn] = __builtin_amdgcn_mfma_f32_16x16x32_bf16(
                    av.v, bf[fn], acc[fm][fn], 0, 0, 0);
        }

        #pragma unroll
        for (int fn = 0; fn < 2; ++fn) {
            int oc = wn * 32 + fn * 16 + c16;
            float bb = fn ? bb1 : bb0;
            #pragma unroll
            for (int fm = 0; fm < 4; ++fm) {
                f32x4 a4 = acc[fm][fn];
                float m = fmaxf(fmaxf(a4[0], a4[1]), fmaxf(a4[2], a4[3]));
                sm_o[(fm * 16 + pxl) * 64 + oc] = f2bf(fmaxf(m + bb, 0.f));
            }
        }
        __syncthreads();
        {
            int row = tid >> 7;        // 0..3 local pooled row
            int off = tid & 127;       // 128 x 16B = 2KB per row
            uint4 v = *(const uint4*)(sm_o + row * (16 * 64) + off * 8);
            int py = TY * 16 + s * 4 + row;
            uint4* dst = (uint4*)(mid + ((size_t)(b * HMID + py) * WMID + tx * 16) * C1) + off;
            *dst = v;
        }
        __syncthreads();               // sm_o free for next subtile
    }
}

// ---------------------------------------------------------------------------
// Kernel B: conv2 bf16 MFMA — FROZEN (R10/R12 structure: packed Wt2,
// global_load_lds staging, dual register prefetch, 98us / MfmaUtil 33%).
// ---------------------------------------------------------------------------
__global__ __launch_bounds__(512, 2)
void k_conv2_mfma(const ushort* __restrict__ mid, const ushort* __restrict__ Wt2,
                  const float* __restrict__ b2, const ushort* __restrict__ zp,
                  ushort* __restrict__ feat)
{
    __shared__ uint4 sm_in[512 * 6];   // 48KB; slots 0..2719 = 340 pos x 8 granules

    const int tid = threadIdx.x;
    const int tx = blockIdx.x;         // 0..7   (32 conv cols each)
    const int ty = blockIdx.y;         // 0..31  (8 conv rows each)
    const int b  = blockIdx.z;

    const int cy0 = ty * 8, cx0 = tx * 32;

    #pragma unroll
    for (int i = 0; i < 6; ++i) {
        int t   = i * 512 + tid;
        int pos = t >> 3, g = t & 7;
        int hy  = pos / 34, hx = pos - hy * 34;
        int gy  = cy0 - 1 + hy, gx = cx0 - 1 + hx;
        bool ok = (t < 2720) && ((unsigned)gy < (unsigned)HMID)
                             && ((unsigned)gx < (unsigned)WMID);
        const ushort* src = ok
            ? mid + (((size_t)(b * HMID + gy) * WMID + gx) * C1 + (g ^ (pos & 7)) * 8)
            : zp;
        __builtin_amdgcn_global_load_lds((const GLOBAL_AS void*)src,
                                         (LDS_AS void*)&sm_in[t], 16, 0, 0);
    }
    __syncthreads();

    const int l   = tid & 63;
    const int wid = tid >> 6;
    const int wm  = wid & 3;        // x-offset wm*8
    const int wn  = wid >> 2;       // oc-offset wn*64
    const int c16 = l & 15;
    const int hi  = l >> 4;
    const int ylane = (c16 >> 1) & 1;
    const int xlane = ((c16 >> 2) << 1) | (c16 & 1);
    const int pos00 = ylane * 34 + wm * 8 + xlane;
    const ushort* wlane = Wt2 + (wn * 64 + c16) * 32 + hi * 8;

    f32x4 acc[4][4] = {};
    short8 acur[4], anxt[4], bcur[4], bnxt[4];

    #pragma unroll
    for (int fm = 0; fm < 4; ++fm) {
        int pos = pos00 + fm * 68;
        acur[fm] = __builtin_bit_cast(short8, sm_in[pos * 8 + (hi ^ (pos & 7))]);
    }
    #pragma unroll
    for (int fn = 0; fn < 4; ++fn)
        bcur[fn] = *(const short8*)(wlane + fn * 512);

    #pragma unroll
    for (int c = 0; c < 18; ++c) {             // chunk: tap = c>>1, k0 = c&1
        const int cn   = (c < 17) ? c + 1 : 17;
        const int tapn = cn >> 1, k0n = cn & 1;
        const int dyn  = tapn / 3, dxn = tapn - 3 * dyn;
        #pragma unroll
        for (int fm = 0; fm < 4; ++fm) {       // prefetch next A (LDS)
            int pos = pos00 + dyn * 34 + dxn + fm * 68;
            int gi  = (hi + k0n * 4) ^ (pos & 7);
            anxt[fm] = __builtin_bit_cast(short8, sm_in[pos * 8 + gi]);
        }
        const ushort* wnp = wlane + cn * 4096;
        #pragma unroll
        for (int fn = 0; fn < 4; ++fn)         // prefetch next B (L2, 1KB dense)
            bnxt[fn] = *(const short8*)(wnp + fn * 512);

        __builtin_amdgcn_s_setprio(1);
        #pragma unroll
        for (int fm = 0; fm < 4; ++fm)
            #pragma unroll
            for (int fn = 0; fn < 4; ++fn)
                acc[fm][fn] = __builtin_amdgcn_mfma_f32_16x16x32_bf16(
                    acur[fm], bcur[fn], acc[fm][fn], 0, 0, 0);
        __builtin_amdgcn_s_setprio(0);

        #pragma unroll
        for (int q = 0; q < 4; ++q) { acur[q] = anxt[q]; bcur[q] = bnxt[q]; }
    }

    __syncthreads();                       // all waves done reading sm_in
    ushort* sm_o = (ushort*)sm_in;         // reuse: 4*16*128*2B = 16KB
    const int pxl = wm * 4 + hi;
    #pragma unroll
    for (int fn = 0; fn < 4; ++fn) {
        int oc = wn * 64 + fn * 16 + c16;
        float bb = b2[oc];
        #pragma unroll
        for (int fm = 0; fm < 4; ++fm) {
            f32x4 a4 = acc[fm][fn];
            float m = fmaxf(fmaxf(a4[0], a4[1]), fmaxf(a4[2], a4[3]));
            sm_o[(fm * 16 + pxl) * 128 + oc] = f2bf(fmaxf(m + bb, 0.f));
        }
    }
    __syncthreads();
    const int py0 = ty * 4;
    #pragma unroll
    for (int pass = 0; pass < 2; ++pass) {
        int idx = pass * 512 + tid;        // 0..1023
        int row = idx >> 8;                // 0..3
        int off = idx & 255;               // 256 x 16B = 4KB per row
        uint4 v = *(const uint4*)(sm_o + row * (16 * 128) + off * 8);
        uint4* dst = (uint4*)(feat + ((size_t)(b * HFT + py0 + row) * WFT + tx * 16) * C2) + off;
        *dst = v;
    }
}

// ---------------------------------------------------------------------------
// Kernel C: ROI crop + SPP. 2 blocks/ROI (64-ch halves), 256 thr.
// Thread = (ch-quad cq 0..15, 8x8-block blk 0..15); uint2 loads (4 ch/lane)
// halve the load count vs the uint version. 16 lanes x 8B = 128B runs.
// ---------------------------------------------------------------------------
__global__ __launch_bounds__(256)
void k_roi_spp(const ushort* __restrict__ feat, const int* __restrict__ rois,
               ushort* __restrict__ spp)
{
    __shared__ float sm_blk[64 * 17];      // [ch_local][blk], pad 17

    const int tid = threadIdx.x;
    const int roi = blockIdx.x >> 1;
    const int cg  = blockIdx.x & 1;

    const int bi = rois[roi * 5 + 0];
    int xm = (int)roundf((float)rois[roi * 5 + 1] * 0.25f);
    int ym = (int)roundf((float)rois[roi * 5 + 2] * 0.25f);
    xm = min(max(xm, 0), WFT - ROI_FT);
    ym = min(max(ym, 0), HFT - ROI_FT);

    const int cq  = tid & 15;              // ch-quad within 64-ch half
    const int blk = tid >> 4;              // 0..15 (by,bx) 8x8 block
    const int by  = blk >> 2, bx = blk & 3;
    const int ch0 = cg * 64 + cq * 4;

    const ushort* base = feat
        + ((size_t)((bi * HFT + ym + by * 8)) * WFT + xm + bx * 8) * C2 + ch0;

    float mm[4];
    #pragma unroll
    for (int q = 0; q < 4; ++q) mm[q] = -INFINITY;

    #pragma unroll
    for (int y = 0; y < 8; ++y) {
        const ushort* rowp = base + (size_t)y * (WFT * C2);
        #pragma unroll
        for (int j = 0; j < 8; ++j) {
            uint2 v = *(const uint2*)(rowp + (size_t)j * C2);
            mm[0] = fmaxf(mm[0], __builtin_bit_cast(float, v.x << 16));
            mm[1] = fmaxf(mm[1], __builtin_bit_cast(float, v.x & 0xffff0000u));
            mm[2] = fmaxf(mm[2], __builtin_bit_cast(float, v.y << 16));
            mm[3] = fmaxf(mm[3], __builtin_bit_cast(float, v.y & 0xffff0000u));
        }
    }
    #pragma unroll
    for (int q = 0; q < 4; ++q)
        sm_blk[(cq * 4 + q) * 17 + blk] = mm[q];
    __syncthreads();

    if (tid < 64) {
        float v[16];
        #pragma unroll
        for (int k = 0; k < 16; ++k) v[k] = sm_blk[tid * 17 + k];
        ushort* o = spp + (size_t)roi * SPP_DIM;
        const int cc = cg * 64 + tid;
        #pragma unroll
        for (int k = 0; k < 16; ++k) o[640 + cc * 16 + k] = f2bf(v[k]);
        float g = -INFINITY;
        #pragma unroll
        for (int qy = 0; qy < 2; ++qy) {
            #pragma unroll
            for (int qx = 0; qx < 2; ++qx) {
                float q = fmaxf(fmaxf(v[(2 * qy) * 4 + 2 * qx],     v[(2 * qy) * 4 + 2 * qx + 1]),
                                fmaxf(v[(2 * qy + 1) * 4 + 2 * qx], v[(2 * qy + 1) * 4 + 2 * qx + 1]));
                o[128 + cc * 4 + qy * 2 + qx] = f2bf(q);
                g = fmaxf(g, q);
            }
        }
        o[cc] = f2bf(g);
    }
}

// ---------------------------------------------------------------------------
// Kernel D: FC1 via bf16 MFMA, K-split x4 across 4 waves + LDS reduce.
// Was 32 waves total @ 84 serial latency-bound iters; now 128 waves @ 21.
// ---------------------------------------------------------------------------
__global__ __launch_bounds__(256)
void k_fc1(const ushort* __restrict__ spp, const ushort* __restrict__ f1T,
           const float* __restrict__ bias, ushort* __restrict__ h)
{
    __shared__ float sm_r[4 * 64 * 33];    // [wave][lane][val], pad 33: 33.8KB

    const int m0 = blockIdx.x * 32;     // 8 blocks
    const int n0 = blockIdx.y * 64;     // 4 blocks
    const int tid = threadIdx.x;
    const int wv  = tid >> 6;           // 0..3 — K-slice
    const int l   = tid & 63;
    const int c16 = l & 15, hi = l >> 4;

    const int kbase = wv * 672;         // 4 x 672 = 2688

    const ushort* ap0 = spp + (size_t)(m0 + c16) * SPP_DIM + kbase + hi * 8;
    const ushort* ap1 = ap0 + 16 * SPP_DIM;
    const ushort* bp[4];
    #pragma unroll
    for (int fn = 0; fn < 4; ++fn)
        bp[fn] = f1T + (size_t)(n0 + fn * 16 + c16) * SPP_DIM + kbase + hi * 8;

    f32x4 acc[2][4] = {};
    short8 a[2], bb[4], an[2], bn[4];
    a[0] = *(const short8*)(ap0);
    a[1] = *(const short8*)(ap1);
    #pragma unroll
    for (int fn = 0; fn < 4; ++fn) bb[fn] = *(const short8*)(bp[fn]);

    for (int k0 = 0; k0 < 672; k0 += 32) {
        int kn = (k0 + 32 < 672) ? k0 + 32 : k0;
        an[0] = *(const short8*)(ap0 + kn);
        an[1] = *(const short8*)(ap1 + kn);
        #pragma unroll
        for (int fn = 0; fn < 4; ++fn) bn[fn] = *(const short8*)(bp[fn] + kn);
        #pragma unroll
        for (int fm = 0; fm < 2; ++fm)
            #pragma unroll
            for (int fn = 0; fn < 4; ++fn)
                acc[fm][fn] = __builtin_amdgcn_mfma_f32_16x16x32_bf16(
                    a[fm], bb[fn], acc[fm][fn], 0, 0, 0);
        a[0] = an[0]; a[1] = an[1];
        #pragma unroll
        for (int fn = 0; fn < 4; ++fn) bb[fn] = bn[fn];
    }

    // write partials: val = (fm*4+fn)*4 + r
    float* smw = sm_r + (wv * 64 + l) * 33;
    #pragma unroll
    for (int fm = 0; fm < 2; ++fm)
        #pragma unroll
        for (int fn = 0; fn < 4; ++fn) {
            f32x4 a4 = acc[fm][fn];
            #pragma unroll
            for (int r = 0; r < 4; ++r)
                smw[(fm * 4 + fn) * 4 + r] = a4[r];
        }
    __syncthreads();

    if (wv == 0) {
        #pragma unroll
        for (int fn = 0; fn < 4; ++fn) {
            int col = n0 + fn * 16 + c16;
            float bv = bias[col];
            #pragma unroll
            for (int fm = 0; fm < 2; ++fm) {
                #pragma unroll
                for (int r = 0; r < 4; ++r) {
                    int v = (fm * 4 + fn) * 4 + r;
                    float s = sm_r[l * 33 + v]
                            + sm_r[(64 + l) * 33 + v]
                            + sm_r[(128 + l) * 33 + v]
                            + sm_r[(192 + l) * 33 + v];
                    int row = m0 + fm * 16 + hi * 4 + r;
                    h[row * FC1_OUT + col] = f2bf(fmaxf(s + bv, 0.f));
                }
            }
        }
    }
}

// ---------------------------------------------------------------------------
// Kernel E: FC2 via bf16 MFMA + bias -> out f32 [256][1000].
// ---------------------------------------------------------------------------
__global__ __launch_bounds__(64)
void k_fc2(const ushort* __restrict__ h, const ushort* __restrict__ f2T,
           const float* __restrict__ bias, float* __restrict__ out)
{
    const int m0 = blockIdx.x * 32;     // 8 blocks
    const int n0 = blockIdx.y * 64;     // 16 blocks (N padded to 1024)
    const int l  = threadIdx.x;
    const int c16 = l & 15, hi = l >> 4;

    f32x4 acc[2][4] = {};
    #pragma unroll
    for (int k0 = 0; k0 < FC1_OUT; k0 += 32) {
        short8 a[2], bb[4];
        #pragma unroll
        for (int fm = 0; fm < 2; ++fm)
            a[fm] = *(const short8*)(h + (size_t)(m0 + fm * 16 + c16) * FC1_OUT + k0 + hi * 8);
        #pragma unroll
        for (int fn = 0; fn < 4; ++fn)
            bb[fn] = *(const short8*)(f2T + (size_t)(n0 + fn * 16 + c16) * FC1_OUT + k0 + hi * 8);
        #pragma unroll
        for (int fm = 0; fm < 2; ++fm)
            #pragma unroll
            for (int fn = 0; fn < 4; ++fn)
                acc[fm][fn] = __builtin_amdgcn_mfma_f32_16x16x32_bf16(
                    a[fm], bb[fn], acc[fm][fn], 0, 0, 0);
    }
    #pragma unroll
    for (int fn = 0; fn < 4; ++fn) {
        int col = n0 + fn * 16 + c16;
        if (col < NCLS) {
            float bv = bias[col];
            #pragma unroll
            for (int fm = 0; fm < 2; ++fm) {
                f32x4 a4 = acc[fm][fn];
                #pragma unroll
                for (int r = 0; r < 4; ++r) {
                    int row = m0 + fm * 16 + hi * 4 + r;
                    out[row * NCLS + col] = a4[r] + bv;
                }
            }
        }
    }
}

// ---------------------------------------------------------------------------
extern "C" void kernel_launch(void* const* d_in, const int* in_sizes, int n_in,
                              void* d_out, int out_size, void* d_ws, size_t ws_size,
                              hipStream_t stream)
{
    const float* x     = (const float*)d_in[0];
    const int*   rois  = (const int*)  d_in[1];
    const float* w1    = (const float*)d_in[2];
    const float* b1    = (const float*)d_in[3];
    const float* w2    = (const float*)d_in[4];
    const float* b2    = (const float*)d_in[5];
    const float* fc1_w = (const float*)d_in[6];
    const float* fc1_b = (const float*)d_in[7];
    const float* fc2_w = (const float*)d_in[8];
    const float* fc2_b = (const float*)d_in[9];
    float* out = (float*)d_out;

    // workspace: mid | Wt2 | zp | feat | spp | h | f1T | f2T
    ushort* midb  = (ushort*)d_ws;
    ushort* Wt2   = midb  + (size_t)NB * HMID * WMID * C1;          // 33.55M
    ushort* zp    = Wt2   + 73728;                                  // 64
    ushort* featb = zp    + 64;
    ushort* sppb  = featb + (size_t)NB * HFT * WFT * C2;            // 16.78M
    ushort* hb    = sppb  + (size_t)NROIS * SPP_DIM;                // 688128
    ushort* f1T   = hb    + NROIS * FC1_OUT;                        // 65536
    ushort* f2T   = f1T   + (size_t)FC1_OUT * SPP_DIM;              // 688128

    k_conv1_prep<<<dim3(16, 16, 10), 512, 0, stream>>>(
        x, w1, b1, midb, w2, fc1_w, fc2_w, Wt2, zp, f1T, f2T);
    k_conv2_mfma<<<dim3(8, 32, NB),  512, 0, stream>>>(midb, Wt2, b2, zp, featb);
    k_roi_spp   <<<dim3(NROIS * 2),  256, 0, stream>>>(featb, rois, sppb);
    k_fc1       <<<dim3(8, 4),       256, 0, stream>>>(sppb, f1T, fc1_b, hb);
    k_fc2       <<<dim3(8, 16),      64,  0, stream>>>(hb, f2T, fc2_b, out);
}

// Round 14
// 145.053 us; speedup vs baseline: 3.2229x; 1.0915x over previous
//
#include <hip/hip_runtime.h>
#include <math.h>

// ---- problem constants ----
#define NB      8
#define C_IN    3
#define HIMG    512
#define WIMG    512
#define C1      64      // conv1 out channels
#define HMID    256     // after pool1
#define WMID    256
#define C2      128     // conv2 out channels (C_FEAT)
#define HFT     128     // after pool2
#define WFT     128
#define NROIS   256
#define ROI_FT  32
#define SPP_DIM 2688    // 128*(1+4+16)
#define FC1_OUT 256
#define NCLS    1000

typedef unsigned short ushort;
typedef __attribute__((ext_vector_type(8))) short short8;
typedef __attribute__((ext_vector_type(4))) float f32x4;

#define GLOBAL_AS __attribute__((address_space(1)))
#define LDS_AS    __attribute__((address_space(3)))

static __device__ __forceinline__ ushort f2bf(float f) {
    unsigned u = __builtin_bit_cast(unsigned, f);
    unsigned r = (u + 0x7fffu + ((u >> 16) & 1u)) >> 16;   // RNE
    return (ushort)r;
}
static __device__ __forceinline__ float bf2f(ushort u) {
    return __builtin_bit_cast(float, (unsigned)u << 16);
}

// ---------------------------------------------------------------------------
// Kernel A+P: conv1 bf16 MFMA (z<8) fused with weight prep (z>=8).
// [byte-identical to R12/R13]
// ---------------------------------------------------------------------------
__global__ __launch_bounds__(512, 4)
void k_conv1_prep(const float* __restrict__ x, const float* __restrict__ w1,
                  const float* __restrict__ b1, ushort* __restrict__ mid,
                  const float* __restrict__ w2, const float* __restrict__ fc1w,
                  const float* __restrict__ fc2w, ushort* __restrict__ Wt2,
                  ushort* __restrict__ zp, ushort* __restrict__ f1T,
                  ushort* __restrict__ f2T)
{
    __shared__ ushort sm_x[3 * 34 * 36 + 8];     // conv1: 34 rows x 36 x 3 ci
    __shared__ ushort sm_o[4 * 16 * 64];         // conv1: pooled out 8KB
    __shared__ float  sm_t[64][65];              // prep: transpose tile 16.6KB

    const int tid = threadIdx.x;

    if (blockIdx.z >= 8) {                       // ================ PREP ====
        int pid = (blockIdx.z - 8) * 256 + blockIdx.y * 16 + blockIdx.x;
        if (pid >= 376) return;
        if (pid < 144) {                         // ---- w2 -> Wt2 ----
            if (pid == 0 && tid < 64) zp[tid] = 0;
            int i = pid * 512 + tid;             // 73728 = 144*512
            int c   = i >> 12;
            int rem = i & 4095;
            int oc  = rem >> 5;
            int s   = rem & 31;
            int tap = c >> 1;
            int ci  = (c & 1) * 32 + s;
            Wt2[i] = f2bf(w2[(oc * 64 + ci) * 9 + tap]);
        } else if (pid < 312) {                  // ---- fc1_w transpose ----
            int j  = pid - 144;                  // 0..167 (42 x 4)
            int k0 = (j % 42) * 64;
            int n0 = (j / 42) * 64;
            #pragma unroll
            for (int s = 0; s < 8; ++s) {
                int idx = s * 512 + tid;
                int lk = idx >> 6, ln = idx & 63;
                sm_t[lk][ln] = fc1w[(size_t)(k0 + lk) * FC1_OUT + n0 + ln];
            }
            __syncthreads();
            #pragma unroll
            for (int s = 0; s < 8; ++s) {
                int idx = s * 512 + tid;
                int ln = idx >> 6, lk = idx & 63;
                f1T[(size_t)(n0 + ln) * SPP_DIM + k0 + lk] = f2bf(sm_t[lk][ln]);
            }
        } else {                                 // ---- fc2_w transpose ----
            int j  = pid - 312;                  // 0..63 (4 x 16)
            int k0 = (j & 3) * 64;
            int n0 = (j >> 2) * 64;
            #pragma unroll
            for (int s = 0; s < 8; ++s) {
                int idx = s * 512 + tid;
                int lk = idx >> 6, ln = idx & 63;
                sm_t[lk][ln] = (n0 + ln < NCLS) ? fc2w[(size_t)(k0 + lk) * NCLS + n0 + ln] : 0.f;
            }
            __syncthreads();
            #pragma unroll
            for (int s = 0; s < 8; ++s) {
                int idx = s * 512 + tid;
                int ln = idx >> 6, lk = idx & 63;
                f2T[(size_t)(n0 + ln) * FC1_OUT + k0 + lk] = f2bf(sm_t[lk][ln]);
            }
        }
        return;
    }

    // ================ CONV1 (4 y-subtiles per block) ====
    const int tx = blockIdx.x;    // 0..15 (32 conv cols)
    const int TY = blockIdx.y;    // 0..15 (32 conv rows = 4 subtiles)
    const int b  = blockIdx.z;

    const int cy0 = TY * 32, cx0 = tx * 32;

    for (int t = tid; t < 3 * 34 * 34; t += 512) {
        int ci  = t / 1156;
        int rem = t - ci * 1156;
        int r = rem / 34, c = rem - r * 34;
        int gy = cy0 - 1 + r, gx = cx0 - 1 + c;
        float v = 0.f;
        if ((unsigned)gy < (unsigned)HIMG && (unsigned)gx < (unsigned)WIMG)
            v = x[((b * C_IN + ci) * HIMG + gy) * WIMG + gx];
        sm_x[ci * 1224 + r * 36 + c] = f2bf(v);
    }

    const int l   = tid & 63;
    const int wid = tid >> 6;
    const int wm  = wid & 3;       // conv-x offset wm*8
    const int wn  = wid >> 2;      // oc offset wn*32
    const int c16 = l & 15;
    const int hi  = l >> 4;
    const int ylane = (c16 >> 1) & 1;
    const int xlane = ((c16 >> 2) << 1) | (c16 & 1);
    const int xloc  = wm * 8 + xlane;

    int offj[8];
    #pragma unroll
    for (int j = 0; j < 8; ++j) {
        int k = hi * 8 + j;
        int tap = k / 3, ci = k - 3 * tap;
        int dy = tap / 3, dx = tap - 3 * dy;
        offj[j] = (k < 27) ? (ci * 1224 + dy * 36 + dx) : 0;
    }

    // weight fragments straight from w1 (fp32, L2-hot)
    short8 bf[2];
    #pragma unroll
    for (int fn = 0; fn < 2; ++fn) {
        int oc = wn * 32 + fn * 16 + c16;
        union { ushort u[8]; short8 v; } wv;
        #pragma unroll
        for (int j = 0; j < 8; ++j) {
            int k = hi * 8 + j;
            float w = 0.f;
            if (k < 27) {
                int tap = k / 3, ci = k - 3 * tap;
                w = w1[oc * 27 + ci * 9 + tap];
            }
            wv.u[j] = f2bf(w);
        }
        bf[fn] = wv.v;
    }
    __syncthreads();               // sm_x staged (overlaps weight gather)

    const int pxl = wm * 4 + hi;   // pooled px local 0..15
    float bb0 = b1[wn * 32 + c16];
    float bb1 = b1[wn * 32 + 16 + c16];

    for (int s = 0; s < 4; ++s) {
        f32x4 acc[4][2] = {};
        #pragma unroll
        for (int fm = 0; fm < 4; ++fm) {
            int base = (s * 8 + 2 * fm + ylane) * 36 + xloc;
            union { ushort u[8]; short8 v; } av;
            #pragma unroll
            for (int j = 0; j < 8; ++j) av.u[j] = sm_x[offj[j] + base];
            #pragma unroll
            for (int fn = 0; fn < 2; ++fn)
                acc[fm][fn] = __builtin_amdgcn_mfma_f32_16x16x32_bf16(
                    av.v, bf[fn], acc[fm][fn], 0, 0, 0);
        }

        #pragma unroll
        for (int fn = 0; fn < 2; ++fn) {
            int oc = wn * 32 + fn * 16 + c16;
            float bb = fn ? bb1 : bb0;
            #pragma unroll
            for (int fm = 0; fm < 4; ++fm) {
                f32x4 a4 = acc[fm][fn];
                float m = fmaxf(fmaxf(a4[0], a4[1]), fmaxf(a4[2], a4[3]));
                sm_o[(fm * 16 + pxl) * 64 + oc] = f2bf(fmaxf(m + bb, 0.f));
            }
        }
        __syncthreads();
        {
            int row = tid >> 7;        // 0..3 local pooled row
            int off = tid & 127;       // 128 x 16B = 2KB per row
            uint4 v = *(const uint4*)(sm_o + row * (16 * 64) + off * 8);
            int py = TY * 16 + s * 4 + row;
            uint4* dst = (uint4*)(mid + ((size_t)(b * HMID + py) * WMID + tx * 16) * C1) + off;
            *dst = v;
        }
        __syncthreads();               // sm_o free for next subtile
    }
}

// ---------------------------------------------------------------------------
// Kernel B: conv2 bf16 MFMA — fm=8/fn=2 re-tiling of the R10 structure.
// Waves: 2 x-halves (wm2) x 4 oc-quarters (wn4). Per wave per chunk:
// 8 A ds_reads + 2 B global loads + 16 MFMA (acc[2][4][2] = 64 AGPR, same).
// B L1 traffic per CU per chunk HALVED (32KB -> 16KB) — the binding resource
// per the R10 packing win and the per-CU cycle model.
// ---------------------------------------------------------------------------
__global__ __launch_bounds__(512, 2)
void k_conv2_mfma(const ushort* __restrict__ mid, const ushort* __restrict__ Wt2,
                  const float* __restrict__ b2, const ushort* __restrict__ zp,
                  ushort* __restrict__ feat)
{
    __shared__ uint4 sm_in[512 * 6];   // 48KB; slots 0..2719 = 340 pos x 8 granules

    const int tid = threadIdx.x;
    const int tx = blockIdx.x;         // 0..7   (32 conv cols each)
    const int ty = blockIdx.y;         // 0..31  (8 conv rows each)
    const int b  = blockIdx.z;

    const int cy0 = ty * 8, cx0 = tx * 32;

    // ---- stage halo tile: async global->LDS, source pre-swizzled ----
    #pragma unroll
    for (int i = 0; i < 6; ++i) {
        int t   = i * 512 + tid;
        int pos = t >> 3, g = t & 7;
        int hy  = pos / 34, hx = pos - hy * 34;
        int gy  = cy0 - 1 + hy, gx = cx0 - 1 + hx;
        bool ok = (t < 2720) && ((unsigned)gy < (unsigned)HMID)
                             && ((unsigned)gx < (unsigned)WMID);
        const ushort* src = ok
            ? mid + (((size_t)(b * HMID + gy) * WMID + gx) * C1 + (g ^ (pos & 7)) * 8)
            : zp;
        __builtin_amdgcn_global_load_lds((const GLOBAL_AS void*)src,
                                         (LDS_AS void*)&sm_in[t], 16, 0, 0);
    }
    __syncthreads();

    // ---- wave / lane decomposition: wn4 = oc quarter, wm2 = x half ----
    const int l   = tid & 63;
    const int wid = tid >> 6;
    const int wn4 = wid & 3;        // oc-offset wn4*32
    const int wm2 = wid >> 2;       // x-offset wm2*16
    const int c16 = l & 15;
    const int hi  = l >> 4;
    const int ylane = (c16 >> 1) & 1;
    const int xlane = ((c16 >> 2) << 1) | (c16 & 1);
    // A-frag base for xw (0..1): positions x = wm2*16 + xw*8 + xlane
    const int posb0 = ylane * 34 + wm2 * 16 + xlane;          // xw=0
    const ushort* wlane = Wt2 + (wn4 * 32 + c16) * 32 + hi * 8;

    f32x4 acc[2][4][2] = {};           // [xw][fm][fn]
    short8 acur[2][4], anxt[2][4], bcur[2], bnxt[2];

    // prologue: chunk 0 (tap 0, k0 0)
    #pragma unroll
    for (int xw = 0; xw < 2; ++xw)
        #pragma unroll
        for (int fm = 0; fm < 4; ++fm) {
            int pos = posb0 + xw * 8 + fm * 68;
            acur[xw][fm] = __builtin_bit_cast(short8, sm_in[pos * 8 + (hi ^ (pos & 7))]);
        }
    #pragma unroll
    for (int fn = 0; fn < 2; ++fn)
        bcur[fn] = *(const short8*)(wlane + fn * 512);

    #pragma unroll
    for (int c = 0; c < 18; ++c) {             // chunk: tap = c>>1, k0 = c&1
        const int cn   = (c < 17) ? c + 1 : 17;
        const int tapn = cn >> 1, k0n = cn & 1;
        const int dyn  = tapn / 3, dxn = tapn - 3 * dyn;
        #pragma unroll
        for (int xw = 0; xw < 2; ++xw)         // prefetch next A (LDS): 8 reads
            #pragma unroll
            for (int fm = 0; fm < 4; ++fm) {
                int pos = posb0 + xw * 8 + dyn * 34 + dxn + fm * 68;
                int gi  = (hi + k0n * 4) ^ (pos & 7);
                anxt[xw][fm] = __builtin_bit_cast(short8, sm_in[pos * 8 + gi]);
            }
        const ushort* wnp = wlane + cn * 4096;
        #pragma unroll
        for (int fn = 0; fn < 2; ++fn)         // prefetch next B: 2 loads (1KB dense)
            bnxt[fn] = *(const short8*)(wnp + fn * 512);

        __builtin_amdgcn_s_setprio(1);
        #pragma unroll
        for (int xw = 0; xw < 2; ++xw)
            #pragma unroll
            for (int fm = 0; fm < 4; ++fm)
                #pragma unroll
                for (int fn = 0; fn < 2; ++fn)
                    acc[xw][fm][fn] = __builtin_amdgcn_mfma_f32_16x16x32_bf16(
                        acur[xw][fm], bcur[fn], acc[xw][fm][fn], 0, 0, 0);
        __builtin_amdgcn_s_setprio(0);

        #pragma unroll
        for (int xw = 0; xw < 2; ++xw)
            #pragma unroll
            for (int fm = 0; fm < 4; ++fm) acur[xw][fm] = anxt[xw][fm];
        bcur[0] = bnxt[0]; bcur[1] = bnxt[1];
    }

    // ---- epilogue: pool 2x2 in-lane -> LDS [py][px][oc] -> linear stores ----
    __syncthreads();                       // all waves done reading sm_in
    ushort* sm_o = (ushort*)sm_in;         // reuse: 4*16*128*2B = 16KB
    #pragma unroll
    for (int fn = 0; fn < 2; ++fn) {
        int oc = wn4 * 32 + fn * 16 + c16;
        float bb = b2[oc];
        #pragma unroll
        for (int xw = 0; xw < 2; ++xw) {
            int pxl = (wm2 * 2 + xw) * 4 + hi;
            #pragma unroll
            for (int fm = 0; fm < 4; ++fm) {
                f32x4 a4 = acc[xw][fm][fn];
                float m = fmaxf(fmaxf(a4[0], a4[1]), fmaxf(a4[2], a4[3]));
                sm_o[(fm * 16 + pxl) * 128 + oc] = f2bf(fmaxf(m + bb, 0.f));
            }
        }
    }
    __syncthreads();
    const int py0 = ty * 4;
    #pragma unroll
    for (int pass = 0; pass < 2; ++pass) {
        int idx = pass * 512 + tid;        // 0..1023
        int row = idx >> 8;                // 0..3
        int off = idx & 255;               // 256 x 16B = 4KB per row
        uint4 v = *(const uint4*)(sm_o + row * (16 * 128) + off * 8);
        uint4* dst = (uint4*)(feat + ((size_t)(b * HFT + py0 + row) * WFT + tx * 16) * C2) + off;
        *dst = v;
    }
}

// ---------------------------------------------------------------------------
// Kernel C: ROI crop + SPP. [byte-identical to R13]
// ---------------------------------------------------------------------------
__global__ __launch_bounds__(256)
void k_roi_spp(const ushort* __restrict__ feat, const int* __restrict__ rois,
               ushort* __restrict__ spp)
{
    __shared__ float sm_blk[64 * 17];      // [ch_local][blk], pad 17

    const int tid = threadIdx.x;
    const int roi = blockIdx.x >> 1;
    const int cg  = blockIdx.x & 1;

    const int bi = rois[roi * 5 + 0];
    int xm = (int)roundf((float)rois[roi * 5 + 1] * 0.25f);
    int ym = (int)roundf((float)rois[roi * 5 + 2] * 0.25f);
    xm = min(max(xm, 0), WFT - ROI_FT);
    ym = min(max(ym, 0), HFT - ROI_FT);

    const int cq  = tid & 15;              // ch-quad within 64-ch half
    const int blk = tid >> 4;              // 0..15 (by,bx) 8x8 block
    const int by  = blk >> 2, bx = blk & 3;
    const int ch0 = cg * 64 + cq * 4;

    const ushort* base = feat
        + ((size_t)((bi * HFT + ym + by * 8)) * WFT + xm + bx * 8) * C2 + ch0;

    float mm[4];
    #pragma unroll
    for (int q = 0; q < 4; ++q) mm[q] = -INFINITY;

    #pragma unroll
    for (int y = 0; y < 8; ++y) {
        const ushort* rowp = base + (size_t)y * (WFT * C2);
        #pragma unroll
        for (int j = 0; j < 8; ++j) {
            uint2 v = *(const uint2*)(rowp + (size_t)j * C2);
            mm[0] = fmaxf(mm[0], __builtin_bit_cast(float, v.x << 16));
            mm[1] = fmaxf(mm[1], __builtin_bit_cast(float, v.x & 0xffff0000u));
            mm[2] = fmaxf(mm[2], __builtin_bit_cast(float, v.y << 16));
            mm[3] = fmaxf(mm[3], __builtin_bit_cast(float, v.y & 0xffff0000u));
        }
    }
    #pragma unroll
    for (int q = 0; q < 4; ++q)
        sm_blk[(cq * 4 + q) * 17 + blk] = mm[q];
    __syncthreads();

    if (tid < 64) {
        float v[16];
        #pragma unroll
        for (int k = 0; k < 16; ++k) v[k] = sm_blk[tid * 17 + k];
        ushort* o = spp + (size_t)roi * SPP_DIM;
        const int cc = cg * 64 + tid;
        #pragma unroll
        for (int k = 0; k < 16; ++k) o[640 + cc * 16 + k] = f2bf(v[k]);
        float g = -INFINITY;
        #pragma unroll
        for (int qy = 0; qy < 2; ++qy) {
            #pragma unroll
            for (int qx = 0; qx < 2; ++qx) {
                float q = fmaxf(fmaxf(v[(2 * qy) * 4 + 2 * qx],     v[(2 * qy) * 4 + 2 * qx + 1]),
                                fmaxf(v[(2 * qy + 1) * 4 + 2 * qx], v[(2 * qy + 1) * 4 + 2 * qx + 1]));
                o[128 + cc * 4 + qy * 2 + qx] = f2bf(q);
                g = fmaxf(g, q);
            }
        }
        o[cc] = f2bf(g);
    }
}

// ---------------------------------------------------------------------------
// Kernel D: FC1 via bf16 MFMA, K-split x4 + LDS reduce. [byte-identical R13]
// ---------------------------------------------------------------------------
__global__ __launch_bounds__(256)
void k_fc1(const ushort* __restrict__ spp, const ushort* __restrict__ f1T,
           const float* __restrict__ bias, ushort* __restrict__ h)
{
    __shared__ float sm_r[4 * 64 * 33];    // [wave][lane][val], pad 33

    const int m0 = blockIdx.x * 32;     // 8 blocks
    const int n0 = blockIdx.y * 64;     // 4 blocks
    const int tid = threadIdx.x;
    const int wv  = tid >> 6;           // 0..3 — K-slice
    const int l   = tid & 63;
    const int c16 = l & 15, hi = l >> 4;

    const int kbase = wv * 672;         // 4 x 672 = 2688

    const ushort* ap0 = spp + (size_t)(m0 + c16) * SPP_DIM + kbase + hi * 8;
    const ushort* ap1 = ap0 + 16 * SPP_DIM;
    const ushort* bp[4];
    #pragma unroll
    for (int fn = 0; fn < 4; ++fn)
        bp[fn] = f1T + (size_t)(n0 + fn * 16 + c16) * SPP_DIM + kbase + hi * 8;

    f32x4 acc[2][4] = {};
    short8 a[2], bb[4], an[2], bn[4];
    a[0] = *(const short8*)(ap0);
    a[1] = *(const short8*)(ap1);
    #pragma unroll
    for (int fn = 0; fn < 4; ++fn) bb[fn] = *(const short8*)(bp[fn]);

    for (int k0 = 0; k0 < 672; k0 += 32) {
        int kn = (k0 + 32 < 672) ? k0 + 32 : k0;
        an[0] = *(const short8*)(ap0 + kn);
        an[1] = *(const short8*)(ap1 + kn);
        #pragma unroll
        for (int fn = 0; fn < 4; ++fn) bn[fn] = *(const short8*)(bp[fn] + kn);
        #pragma unroll
        for (int fm = 0; fm < 2; ++fm)
            #pragma unroll
            for (int fn = 0; fn < 4; ++fn)
                acc[fm][fn] = __builtin_amdgcn_mfma_f32_16x16x32_bf16(
                    a[fm], bb[fn], acc[fm][fn], 0, 0, 0);
        a[0] = an[0]; a[1] = an[1];
        #pragma unroll
        for (int fn = 0; fn < 4; ++fn) bb[fn] = bn[fn];
    }

    float* smw = sm_r + (wv * 64 + l) * 33;
    #pragma unroll
    for (int fm = 0; fm < 2; ++fm)
        #pragma unroll
        for (int fn = 0; fn < 4; ++fn) {
            f32x4 a4 = acc[fm][fn];
            #pragma unroll
            for (int r = 0; r < 4; ++r)
                smw[(fm * 4 + fn) * 4 + r] = a4[r];
        }
    __syncthreads();

    if (wv == 0) {
        #pragma unroll
        for (int fn = 0; fn < 4; ++fn) {
            int col = n0 + fn * 16 + c16;
            float bv = bias[col];
            #pragma unroll
            for (int fm = 0; fm < 2; ++fm) {
                #pragma unroll
                for (int r = 0; r < 4; ++r) {
                    int v = (fm * 4 + fn) * 4 + r;
                    float s = sm_r[l * 33 + v]
                            + sm_r[(64 + l) * 33 + v]
                            + sm_r[(128 + l) * 33 + v]
                            + sm_r[(192 + l) * 33 + v];
                    int row = m0 + fm * 16 + hi * 4 + r;
                    h[row * FC1_OUT + col] = f2bf(fmaxf(s + bv, 0.f));
                }
            }
        }
    }
}

// ---------------------------------------------------------------------------
// Kernel E: FC2 via bf16 MFMA + bias -> out f32 [256][1000]. [identical]
// ---------------------------------------------------------------------------
__global__ __launch_bounds__(64)
void k_fc2(const ushort* __restrict__ h, const ushort* __restrict__ f2T,
           const float* __restrict__ bias, float* __restrict__ out)
{
    const int m0 = blockIdx.x * 32;     // 8 blocks
    const int n0 = blockIdx.y * 64;     // 16 blocks (N padded to 1024)
    const int l  = threadIdx.x;
    const int c16 = l & 15, hi = l >> 4;

    f32x4 acc[2][4] = {};
    #pragma unroll
    for (int k0 = 0; k0 < FC1_OUT; k0 += 32) {
        short8 a[2], bb[4];
        #pragma unroll
        for (int fm = 0; fm < 2; ++fm)
            a[fm] = *(const short8*)(h + (size_t)(m0 + fm * 16 + c16) * FC1_OUT + k0 + hi * 8);
        #pragma unroll
        for (int fn = 0; fn < 4; ++fn)
            bb[fn] = *(const short8*)(f2T + (size_t)(n0 + fn * 16 + c16) * FC1_OUT + k0 + hi * 8);
        #pragma unroll
        for (int fm = 0; fm < 2; ++fm)
            #pragma unroll
            for (int fn = 0; fn < 4; ++fn)
                acc[fm][fn] = __builtin_amdgcn_mfma_f32_16x16x32_bf16(
                    a[fm], bb[fn], acc[fm][fn], 0, 0, 0);
    }
    #pragma unroll
    for (int fn = 0; fn < 4; ++fn) {
        int col = n0 + fn * 16 + c16;
        if (col < NCLS) {
            float bv = bias[col];
            #pragma unroll
            for (int fm = 0; fm < 2; ++fm) {
                f32x4 a4 = acc[fm][fn];
                #pragma unroll
                for (int r = 0; r < 4; ++r) {
                    int row = m0 + fm * 16 + hi * 4 + r;
                    out[row * NCLS + col] = a4[r] + bv;
                }
            }
        }
    }
}

// ---------------------------------------------------------------------------
extern "C" void kernel_launch(void* const* d_in, const int* in_sizes, int n_in,
                              void* d_out, int out_size, void* d_ws, size_t ws_size,
                              hipStream_t stream)
{
    const float* x     = (const float*)d_in[0];
    const int*   rois  = (const int*)  d_in[1];
    const float* w1    = (const float*)d_in[2];
    const float* b1    = (const float*)d_in[3];
    const float* w2    = (const float*)d_in[4];
    const float* b2    = (const float*)d_in[5];
    const float* fc1_w = (const float*)d_in[6];
    const float* fc1_b = (const float*)d_in[7];
    const float* fc2_w = (const float*)d_in[8];
    const float* fc2_b = (const float*)d_in[9];
    float* out = (float*)d_out;

    // workspace: mid | Wt2 | zp | feat | spp | h | f1T | f2T
    ushort* midb  = (ushort*)d_ws;
    ushort* Wt2   = midb  + (size_t)NB * HMID * WMID * C1;          // 33.55M
    ushort* zp    = Wt2   + 73728;                                  // 64
    ushort* featb = zp    + 64;
    ushort* sppb  = featb + (size_t)NB * HFT * WFT * C2;            // 16.78M
    ushort* hb    = sppb  + (size_t)NROIS * SPP_DIM;                // 688128
    ushort* f1T   = hb    + NROIS * FC1_OUT;                        // 65536
    ushort* f2T   = f1T   + (size_t)FC1_OUT * SPP_DIM;              // 688128

    k_conv1_prep<<<dim3(16, 16, 10), 512, 0, stream>>>(
        x, w1, b1, midb, w2, fc1_w, fc2_w, Wt2, zp, f1T, f2T);
    k_conv2_mfma<<<dim3(8, 32, NB),  512, 0, stream>>>(midb, Wt2, b2, zp, featb);
    k_roi_spp   <<<dim3(NROIS * 2),  256, 0, stream>>>(featb, rois, sppb);
    k_fc1       <<<dim3(8, 4),       256, 0, stream>>>(sppb, f1T, fc1_b, hb);
    k_fc2       <<<dim3(8, 16),      64,  0, stream>>>(hb, f2T, fc2_b, out);
}